// Round 1
// baseline (116090.430 us; speedup 1.0000x reference)
//
#include <hip/hip_runtime.h>
#include <math.h>

constexpr int NV = 50000;    // V
constexpr int NL = 100000;   // 2V literal rows
constexpr int NC = 200000;   // clauses
constexpr int NE = 300000;   // edges per polarity
constexpr int NROUNDS = 26;

__device__ __forceinline__ float sigf(float x) { return 1.0f / (1.0f + expf(-x)); }

// ---------------- MLP layer: y = act(x @ W + b) ----------------
// x:[M][128], W:[128][128] row-major [k][n], b:[128]
// block 256 threads, tile 64 rows x 128 cols, thread tile 8x4
__global__ __launch_bounds__(256) void mlp_layer(
    const float* __restrict__ x, const float* __restrict__ W,
    const float* __restrict__ b, float* __restrict__ y, int M, int relu)
{
    __shared__ float As[64][132];
    __shared__ float Bs[32][128];
    __shared__ float bs[128];
    const int t = threadIdx.x;
    const int rb = blockIdx.x * 64;

    // stage A tile (64x128), coalesced float4
    #pragma unroll
    for (int j = 0; j < 8; j++) {
        int i = t + 256 * j;
        int r = i >> 5, c4 = i & 31;
        int gr = rb + r;
        float4 v = make_float4(0.f, 0.f, 0.f, 0.f);
        if (gr < M) v = *reinterpret_cast<const float4*>(x + (size_t)gr * 128 + c4 * 4);
        *reinterpret_cast<float4*>(&As[r][c4 * 4]) = v;
    }
    if (t < 128) bs[t] = b[t];

    const int tn = t & 31;   // col group: cols tn*4..tn*4+3
    const int tm = t >> 5;   // row group: rows tm*8..tm*8+7
    float acc[8][4];
    #pragma unroll
    for (int q = 0; q < 8; q++)
        #pragma unroll
        for (int c = 0; c < 4; c++) acc[q][c] = 0.f;

    for (int kt = 0; kt < 4; kt++) {
        __syncthreads();
        // stage B k-tile (32x128)
        #pragma unroll
        for (int j = 0; j < 4; j++) {
            int i = t + 256 * j;
            int r = i >> 5, c4 = i & 31;
            *reinterpret_cast<float4*>(&Bs[r][c4 * 4]) =
                *reinterpret_cast<const float4*>(W + (size_t)(kt * 32 + r) * 128 + c4 * 4);
        }
        __syncthreads();
        #pragma unroll
        for (int k4 = 0; k4 < 8; k4++) {
            float bbf[16];
            #pragma unroll
            for (int j = 0; j < 4; j++) {
                float4 bv = *reinterpret_cast<const float4*>(&Bs[k4 * 4 + j][tn * 4]);
                bbf[j * 4 + 0] = bv.x; bbf[j * 4 + 1] = bv.y;
                bbf[j * 4 + 2] = bv.z; bbf[j * 4 + 3] = bv.w;
            }
            #pragma unroll
            for (int q = 0; q < 8; q++) {
                float4 a4 = *reinterpret_cast<const float4*>(&As[tm * 8 + q][kt * 32 + k4 * 4]);
                float af[4] = {a4.x, a4.y, a4.z, a4.w};
                #pragma unroll
                for (int j = 0; j < 4; j++)
                    #pragma unroll
                    for (int c = 0; c < 4; c++)
                        acc[q][c] = fmaf(af[j], bbf[j * 4 + c], acc[q][c]);
            }
        }
    }

    #pragma unroll
    for (int q = 0; q < 8; q++) {
        int gr = rb + tm * 8 + q;
        if (gr < M) {
            float4 o;
            o.x = acc[q][0] + bs[tn * 4 + 0];
            o.y = acc[q][1] + bs[tn * 4 + 1];
            o.z = acc[q][2] + bs[tn * 4 + 2];
            o.w = acc[q][3] + bs[tn * 4 + 3];
            if (relu) {
                o.x = fmaxf(o.x, 0.f); o.y = fmaxf(o.y, 0.f);
                o.z = fmaxf(o.z, 0.f); o.w = fmaxf(o.w, 0.f);
            }
            *reinterpret_cast<float4*>(y + (size_t)gr * 128 + tn * 4) = o;
        }
    }
}

// -------- fused LSTM: gates = sum_seg Aseg @ Wseg[:, co:co+128]^T + bih + bhh --------
// block 512 threads, 32 rows, N=512 gates; thread: 4 rows (tm+8q) x 8 gate-cols
// gate cols of thread: n = tn*2 + u + 128*g  (g: 0=i 1=f 2=g 3=o)
template <int NSEG, bool FLIP1>
__global__ __launch_bounds__(512) void lstm_fused(
    const float* __restrict__ A0, const float* __restrict__ A1, const float* __restrict__ A2,
    const float* __restrict__ W0, const float* __restrict__ W1, const float* __restrict__ W2,
    int w0s, int w1s, int w2s, int c0, int c1, int c2,
    const float* __restrict__ bih, const float* __restrict__ bhh,
    float* __restrict__ c_st, float* __restrict__ h_out)
{
    __shared__ float xbuf[32][132];
    __shared__ float Bs[16][516];
    __shared__ float bsum[512];
    const int t = threadIdx.x;
    const int rb = blockIdx.x * 32;
    bsum[t] = bih[t] + bhh[t];

    const int tn = t & 63;
    const int tm = t >> 6;   // wave index 0..7 -> rows tm+8q
    float acc[4][8];

    const float* Aps[3] = {A0, A1, A2};
    const float* Wps[3] = {W0, W1, W2};
    const int wss[3] = {w0s, w1s, w2s};
    const int cos_[3] = {c0, c1, c2};

    bool first = true;
    #pragma unroll
    for (int seg = 0; seg < NSEG; seg++) {
        __syncthreads();  // previous compute done before xbuf overwrite
        const float* Ap = Aps[seg];
        #pragma unroll
        for (int j = 0; j < 2; j++) {
            int i = t + 512 * j;
            int r = i >> 5, c4 = i & 31;
            int grow = rb + r;
            if (FLIP1 && seg == 1) grow = (grow < NV) ? grow + NV : grow - NV;
            *reinterpret_cast<float4*>(&xbuf[r][c4 * 4]) =
                *reinterpret_cast<const float4*>(Ap + (size_t)grow * 128 + c4 * 4);
        }
        const float* Wp = Wps[seg];
        const int wstride = wss[seg];
        const int co = cos_[seg];
        if (first) {
            __syncthreads();  // bsum + xbuf ready
            #pragma unroll
            for (int q = 0; q < 4; q++)
                #pragma unroll
                for (int s = 0; s < 8; s++)
                    acc[q][s] = bsum[tn * 2 + (s & 1) + 128 * (s >> 1)];
            first = false;
            __syncthreads();  // keep barrier count uniform with stage below
        }
        for (int kt = 0; kt < 8; kt++) {
            if (!(seg == 0 && kt == 0)) __syncthreads();  // prev compute done before Bs overwrite
            // stage Bs[16][512] : Bs[kl][n] = W[n][co + kt*16 + kl]
            {
                int cq = t & 3, n0 = t >> 2;
                #pragma unroll
                for (int p = 0; p < 4; p++) {
                    int n = n0 + 128 * p;
                    float4 v = *reinterpret_cast<const float4*>(
                        Wp + (size_t)n * wstride + co + kt * 16 + cq * 4);
                    Bs[cq * 4 + 0][n] = v.x;
                    Bs[cq * 4 + 1][n] = v.y;
                    Bs[cq * 4 + 2][n] = v.z;
                    Bs[cq * 4 + 3][n] = v.w;
                }
            }
            __syncthreads();
            #pragma unroll
            for (int k4 = 0; k4 < 4; k4++) {
                float4 a4[4];
                #pragma unroll
                for (int q = 0; q < 4; q++)
                    a4[q] = *reinterpret_cast<const float4*>(&xbuf[tm + 8 * q][kt * 16 + k4 * 4]);
                #pragma unroll
                for (int j = 0; j < 4; j++) {
                    float2 b2[4];
                    #pragma unroll
                    for (int g = 0; g < 4; g++)
                        b2[g] = *reinterpret_cast<const float2*>(&Bs[k4 * 4 + j][tn * 2 + 128 * g]);
                    #pragma unroll
                    for (int q = 0; q < 4; q++) {
                        float a = (&a4[q].x)[j];
                        acc[q][0] = fmaf(a, b2[0].x, acc[q][0]);
                        acc[q][1] = fmaf(a, b2[0].y, acc[q][1]);
                        acc[q][2] = fmaf(a, b2[1].x, acc[q][2]);
                        acc[q][3] = fmaf(a, b2[1].y, acc[q][3]);
                        acc[q][4] = fmaf(a, b2[2].x, acc[q][4]);
                        acc[q][5] = fmaf(a, b2[2].y, acc[q][5]);
                        acc[q][6] = fmaf(a, b2[3].x, acc[q][6]);
                        acc[q][7] = fmaf(a, b2[3].y, acc[q][7]);
                    }
                }
            }
        }
    }

    // activations + state update
    #pragma unroll
    for (int q = 0; q < 4; q++) {
        int r = rb + tm + 8 * q;
        int j0 = tn * 2;
        float2 cold = *reinterpret_cast<const float2*>(c_st + (size_t)r * 128 + j0);
        float cn0 = sigf(acc[q][2]) * cold.x + sigf(acc[q][0]) * tanhf(acc[q][4]);
        float cn1 = sigf(acc[q][3]) * cold.y + sigf(acc[q][1]) * tanhf(acc[q][5]);
        float h0 = sigf(acc[q][6]) * tanhf(cn0);
        float h1 = sigf(acc[q][7]) * tanhf(cn1);
        *reinterpret_cast<float2*>(c_st + (size_t)r * 128 + j0) = make_float2(cn0, cn1);
        *reinterpret_cast<float2*>(h_out + (size_t)r * 128 + j0) = make_float2(h0, h1);
    }
}

// -------- scatter-add: out[sidx[e]+s_off] += msg[gidx[e]+g_off], 128 floats/row --------
__global__ __launch_bounds__(256) void scatter_add_k(
    const float* __restrict__ msg, const int* __restrict__ gidx, int g_off,
    const int* __restrict__ sidx, int s_off, float* __restrict__ out)
{
    int idx = blockIdx.x * 256 + threadIdx.x;
    int e = idx >> 5;
    if (e >= NE) return;
    int l = idx & 31;
    int rin = gidx[e] + g_off;
    int rout = sidx[e] + s_off;
    float4 v = *reinterpret_cast<const float4*>(msg + (size_t)rin * 128 + l * 4);
    float* op = out + (size_t)rout * 128 + l * 4;
    atomicAdd(op + 0, v.x);
    atomicAdd(op + 1, v.y);
    atomicAdd(op + 2, v.z);
    atomicAdd(op + 3, v.w);
}

extern "C" void kernel_launch(void* const* d_in, const int* in_sizes, int n_in,
                              void* d_out, int out_size, void* d_ws, size_t ws_size,
                              hipStream_t stream)
{
    const float* l_pos   = (const float*)d_in[0];
    const float* l_neg   = (const float*)d_in[1];
    const float* c_emb   = (const float*)d_in[2];
    const float* l_mlp_W = (const float*)d_in[3];
    const float* l_mlp_b = (const float*)d_in[4];
    const float* c_mlp_W = (const float*)d_in[5];
    const float* c_mlp_b = (const float*)d_in[6];
    const float* l_Wih   = (const float*)d_in[7];
    const float* l_Whh   = (const float*)d_in[8];
    const float* l_bih   = (const float*)d_in[9];
    const float* l_bhh   = (const float*)d_in[10];
    const float* c_Wih   = (const float*)d_in[11];
    const float* c_Whh   = (const float*)d_in[12];
    const float* c_bih   = (const float*)d_in[13];
    const float* c_bhh   = (const float*)d_in[14];
    const int* pos_src   = (const int*)d_in[15];
    const int* pos_dst   = (const int*)d_in[16];
    const int* neg_src   = (const int*)d_in[17];
    const int* neg_dst   = (const int*)d_in[18];

    float* out  = (float*)d_out;
    float* l_hA = out;                      // [NL][128] literal state (final resting place)
    float* c_h  = out + (size_t)NL * 128;   // [NC][128] clause state, updated in place

    float* w = (float*)d_ws;
    float* l_hB  = w; w += (size_t)NL * 128;
    float* l_c   = w; w += (size_t)NL * 128;
    float* c_c   = w; w += (size_t)NC * 128;
    float* l_msg = w; w += (size_t)NL * 128;   // aliased as c2l after consumption
    float* c_msg = w; w += (size_t)NC * 128;
    float* l2c   = w; w += (size_t)NC * 128;   // aliased as MLP intermediate before scatter
    float* c2l = l_msg;
    float* tmp = l2c;

    // init states
    hipMemcpyAsync(l_hA, l_pos, (size_t)NV * 128 * 4, hipMemcpyDeviceToDevice, stream);
    hipMemcpyAsync(l_hA + (size_t)NV * 128, l_neg, (size_t)NV * 128 * 4, hipMemcpyDeviceToDevice, stream);
    hipMemcpyAsync(c_h, c_emb, (size_t)NC * 128 * 4, hipMemcpyDeviceToDevice, stream);
    hipMemsetAsync(l_c, 0, (size_t)NL * 128 * 4, stream);
    hipMemsetAsync(c_c, 0, (size_t)NC * 128 * 4, stream);

    float* l_cur = l_hA;
    float* l_nxt = l_hB;

    for (int r = 0; r < NROUNDS; r++) {
        // literal MLP: l_cur -> l_msg (tmp as intermediate)
        mlp_layer<<<(NL + 63) / 64, 256, 0, stream>>>(l_cur, l_mlp_W + 0 * 128 * 128, l_mlp_b + 0,   l_msg, NL, 1);
        mlp_layer<<<(NL + 63) / 64, 256, 0, stream>>>(l_msg, l_mlp_W + 1 * 128 * 128, l_mlp_b + 128, tmp,   NL, 1);
        mlp_layer<<<(NL + 63) / 64, 256, 0, stream>>>(tmp,   l_mlp_W + 2 * 128 * 128, l_mlp_b + 256, l_msg, NL, 0);
        // clause MLP: c_h -> c_msg (tmp as intermediate; tmp region == l2c, still free)
        mlp_layer<<<NC / 64, 256, 0, stream>>>(c_h,   c_mlp_W + 0 * 128 * 128, c_mlp_b + 0,   c_msg, NC, 1);
        mlp_layer<<<NC / 64, 256, 0, stream>>>(c_msg, c_mlp_W + 1 * 128 * 128, c_mlp_b + 128, tmp,   NC, 1);
        mlp_layer<<<NC / 64, 256, 0, stream>>>(tmp,   c_mlp_W + 2 * 128 * 128, c_mlp_b + 256, c_msg, NC, 0);

        // l2c = seg_sum(pos_msg[pos_src] -> pos_dst) + seg_sum(neg_msg[neg_src] -> neg_dst)
        hipMemsetAsync(l2c, 0, (size_t)NC * 128 * 4, stream);
        scatter_add_k<<<NE * 32 / 256, 256, 0, stream>>>(l_msg, pos_src, 0,  pos_dst, 0, l2c);
        scatter_add_k<<<NE * 32 / 256, 256, 0, stream>>>(l_msg, neg_src, NV, neg_dst, 0, l2c);
        // c2l: rows [0,V) from pos edges, rows [V,2V) from neg edges (reuses l_msg space)
        hipMemsetAsync(c2l, 0, (size_t)NL * 128 * 4, stream);
        scatter_add_k<<<NE * 32 / 256, 256, 0, stream>>>(c_msg, pos_dst, 0, pos_src, 0,  c2l);
        scatter_add_k<<<NE * 32 / 256, 256, 0, stream>>>(c_msg, neg_dst, 0, neg_src, NV, c2l);

        // literal LSTM: x = [c2l | flip(l_cur)], h = l_cur -> l_nxt, l_c in place
        lstm_fused<3, true><<<NL / 32, 512, 0, stream>>>(
            c2l, l_cur, l_cur, l_Wih, l_Wih, l_Whh,
            256, 256, 128, 0, 128, 0, l_bih, l_bhh, l_c, l_nxt);
        // clause LSTM: x = l2c, h = c_h -> c_h in place, c_c in place
        lstm_fused<2, false><<<NC / 32, 512, 0, stream>>>(
            l2c, c_h, nullptr, c_Wih, c_Whh, nullptr,
            128, 128, 0, 0, 0, 0, c_bih, c_bhh, c_c, c_h);

        float* t2 = l_cur; l_cur = l_nxt; l_nxt = t2;
    }
    // after 26 (even) rounds l_cur == l_hA == d_out rows [0,NL); c_h already in d_out.
    (void)in_sizes; (void)n_in; (void)out_size; (void)ws_size;
}

// Round 2
// 80296.863 us; speedup vs baseline: 1.4458x; 1.4458x over previous
//
#include <hip/hip_runtime.h>
#include <math.h>

typedef __attribute__((ext_vector_type(8))) short short8;
typedef __attribute__((ext_vector_type(4))) float f32x4;

constexpr int NV = 50000;    // V
constexpr int NL = 100000;   // 2V literal rows
constexpr int NC = 200000;   // clauses
constexpr int NE = 300000;   // edges per polarity
constexpr int NROUNDS = 26;

__device__ __forceinline__ float sigf(float x) { return 1.0f / (1.0f + expf(-x)); }

// in-register f32 -> bf16 hi/lo split (truncation; combined rel err ~2^-16)
__device__ __forceinline__ void split8(const float* a, short8& h, short8& l) {
#pragma unroll
    for (int j = 0; j < 8; j++) {
        unsigned u = __float_as_uint(a[j]);
        h[j] = (short)(u >> 16);
        float lf = a[j] - __uint_as_float(u & 0xffff0000u);
        l[j] = (short)(__float_as_uint(lf) >> 16);
    }
}

// weight split with RTN on both halves (one-time prep)
__device__ __forceinline__ void splitw(float x, unsigned short* h, unsigned short* l) {
    unsigned u = __float_as_uint(x);
    unsigned hr = (u + 0x7fffu + ((u >> 16) & 1u)) & 0xffff0000u;
    float lf = x - __uint_as_float(hr);
    unsigned ul = __float_as_uint(lf);
    *h = (unsigned short)(hr >> 16);
    *l = (unsigned short)((ul + 0x7fffu + ((ul >> 16) & 1u)) >> 16);
}

// ---- weight prep: MLP W[3][k][n] f32 -> WT[3][n][k] bf16 hi/lo ----
__global__ __launch_bounds__(256) void pack_mlp_k(
    const float* __restrict__ W, unsigned short* __restrict__ Wh, unsigned short* __restrict__ Wl)
{
    int idx = blockIdx.x * 256 + threadIdx.x;
    if (idx >= 3 * 128 * 128) return;
    int L = idx >> 14, r = idx & 16383, n = r >> 7, k = r & 127;
    splitw(W[(L << 14) + (k << 7) + n], &Wh[idx], &Wl[idx]);
}

// ---- weight prep: LSTM [Wih | Whh] -> BT[512][ktot] bf16 hi/lo (already [n][k]) ----
__global__ __launch_bounds__(256) void pack_lstm_k(
    const float* __restrict__ Wih, const float* __restrict__ Whh, int kih, int ktot,
    unsigned short* __restrict__ Wh, unsigned short* __restrict__ Wl)
{
    int idx = blockIdx.x * 256 + threadIdx.x;
    if (idx >= 512 * ktot) return;
    int n = idx / ktot, k = idx - n * ktot;
    float v = (k < kih) ? Wih[n * kih + k] : Whh[(n << 7) + (k - kih)];
    splitw(v, &Wh[idx], &Wl[idx]);
}

// ---------------- fused 3-layer MLP, bf16x3 MFMA ----------------
// block 256 (4 waves), BM=64; wave tile 32 rows x 64 cols (2x4 16x16 frags)
__global__ __launch_bounds__(256, 2) void mlp3(
    const float* __restrict__ x, const unsigned short* __restrict__ Wh,
    const unsigned short* __restrict__ Wl, const float* __restrict__ bias,
    float* __restrict__ y, int M)
{
    __shared__ float Xs[64][132];
    __shared__ unsigned short Bh[128][40];
    __shared__ unsigned short Bl[128][40];
    const int t = threadIdx.x;
    const int rb = blockIdx.x * 64;
    const int lane = t & 63, w = t >> 6, wr = w >> 1, wc = w & 1;
    const int l15 = lane & 15, lg = lane >> 4;

#pragma unroll
    for (int j = 0; j < 8; j++) {
        int i = t + 256 * j;
        int r = i >> 5, c4 = i & 31;
        int gr = rb + r; if (gr >= M) gr = M - 1;
        *reinterpret_cast<float4*>(&Xs[r][c4 * 4]) =
            *reinterpret_cast<const float4*>(x + (size_t)gr * 128 + c4 * 4);
    }

    for (int layer = 0; layer < 3; layer++) {
        f32x4 acc[2][4];
#pragma unroll
        for (int m = 0; m < 2; m++)
#pragma unroll
            for (int nf = 0; nf < 4; nf++) acc[m][nf] = f32x4{0.f, 0.f, 0.f, 0.f};

        for (int kt = 0; kt < 4; kt++) {
            __syncthreads();
            {   // stage B k-tile [128n][32k] hi/lo
                int n = t >> 1, kh = (t & 1) * 16;
                size_t off = (size_t)layer * 16384 + n * 128 + kt * 32 + kh;
                const uint4* sh = reinterpret_cast<const uint4*>(Wh + off);
                const uint4* sl = reinterpret_cast<const uint4*>(Wl + off);
                uint4 h0 = sh[0], h1 = sh[1], l0 = sl[0], l1 = sl[1];
                *reinterpret_cast<uint4*>(&Bh[n][kh]) = h0;
                *reinterpret_cast<uint4*>(&Bh[n][kh + 8]) = h1;
                *reinterpret_cast<uint4*>(&Bl[n][kh]) = l0;
                *reinterpret_cast<uint4*>(&Bl[n][kh + 8]) = l1;
            }
            __syncthreads();
            short8 bh[4], bl[4];
#pragma unroll
            for (int nf = 0; nf < 4; nf++) {
                int n = wc * 64 + nf * 16 + l15;
                bh[nf] = *reinterpret_cast<const short8*>(&Bh[n][lg * 8]);
                bl[nf] = *reinterpret_cast<const short8*>(&Bl[n][lg * 8]);
            }
#pragma unroll
            for (int m = 0; m < 2; m++) {
                int row = wr * 32 + m * 16 + l15;
                float av[8];
                *reinterpret_cast<float4*>(&av[0]) =
                    *reinterpret_cast<const float4*>(&Xs[row][kt * 32 + lg * 8]);
                *reinterpret_cast<float4*>(&av[4]) =
                    *reinterpret_cast<const float4*>(&Xs[row][kt * 32 + lg * 8 + 4]);
                short8 ah, al; split8(av, ah, al);
#pragma unroll
                for (int nf = 0; nf < 4; nf++) {
                    acc[m][nf] = __builtin_amdgcn_mfma_f32_16x16x32_bf16(ah, bh[nf], acc[m][nf], 0, 0, 0);
                    acc[m][nf] = __builtin_amdgcn_mfma_f32_16x16x32_bf16(ah, bl[nf], acc[m][nf], 0, 0, 0);
                    acc[m][nf] = __builtin_amdgcn_mfma_f32_16x16x32_bf16(al, bh[nf], acc[m][nf], 0, 0, 0);
                }
            }
        }
        __syncthreads();
        float bv[4];
#pragma unroll
        for (int nf = 0; nf < 4; nf++) bv[nf] = bias[layer * 128 + wc * 64 + nf * 16 + l15];
        if (layer < 2) {
#pragma unroll
            for (int m = 0; m < 2; m++)
#pragma unroll
                for (int nf = 0; nf < 4; nf++)
#pragma unroll
                    for (int rr = 0; rr < 4; rr++) {
                        float v = fmaxf(acc[m][nf][rr] + bv[nf], 0.f);
                        Xs[wr * 32 + m * 16 + lg * 4 + rr][wc * 64 + nf * 16 + l15] = v;
                    }
        } else {
#pragma unroll
            for (int m = 0; m < 2; m++)
#pragma unroll
                for (int rr = 0; rr < 4; rr++) {
                    int gr = rb + wr * 32 + m * 16 + lg * 4 + rr;
                    if (gr < M) {
#pragma unroll
                        for (int nf = 0; nf < 4; nf++)
                            y[(size_t)gr * 128 + wc * 64 + nf * 16 + l15] = acc[m][nf][rr] + bv[nf];
                    }
                }
        }
    }
}

// ---------------- fused LSTM (gates GEMM bf16x3 + activations) ----------------
// block 512 (8 waves), BM=128; wave tile 32 rows x 256 gate-cols (gate-grouped)
template <int NSTEP, bool FLIP>
__global__ __launch_bounds__(512, 2) void lstm_mfma(
    const float* __restrict__ A0, const float* __restrict__ A1, const float* __restrict__ A2,
    const unsigned short* __restrict__ Bh_g, const unsigned short* __restrict__ Bl_g,
    const float* __restrict__ bih, const float* __restrict__ bhh,
    float* __restrict__ c_st, float* __restrict__ h_out, int M)
{
    constexpr int KTOT = NSTEP * 32;
    __shared__ float Xs[128][36];
    __shared__ unsigned short Bhs[512][40];
    __shared__ unsigned short Bls[512][40];
    __shared__ float bsum[512];
    const int t = threadIdx.x;
    const int rb = blockIdx.x * 128;
    const int lane = t & 63, w = t >> 6, wr = w >> 1, wc = w & 1;
    const int l15 = lane & 15, lg = lane >> 4;
    bsum[t] = bih[t] + bhh[t];

    f32x4 acc[2][16];
#pragma unroll
    for (int m = 0; m < 2; m++)
#pragma unroll
        for (int nr = 0; nr < 16; nr++) acc[m][nr] = f32x4{0.f, 0.f, 0.f, 0.f};

    const int xrow = t >> 2, xc8 = (t & 3) * 8;
    int xgrow = rb + xrow; if (xgrow >= M) xgrow = M - 1;

    for (int kt = 0; kt < NSTEP; kt++) {
        __syncthreads();
        {   // stage X k-tile [128 rows][32 k] f32, segment-select
            int seg = kt >> 2;
            int kb = (kt & 3) * 32 + xc8;
            const float* src; size_t grow = (size_t)xgrow;
            if (NSTEP == 12) {
                if (seg == 0) src = A0;
                else if (seg == 1) {
                    src = A1;
                    if (FLIP) grow = (xgrow < NV) ? (size_t)(xgrow + NV) : (size_t)(xgrow - NV);
                } else src = A2;
            } else {
                src = seg ? A1 : A0;
            }
            const float4* sp = reinterpret_cast<const float4*>(src + grow * 128 + kb);
            float4 v0 = sp[0], v1 = sp[1];
            *reinterpret_cast<float4*>(&Xs[xrow][xc8]) = v0;
            *reinterpret_cast<float4*>(&Xs[xrow][xc8 + 4]) = v1;
        }
        {   // stage B k-tile [512n][32k] hi/lo
            size_t off = (size_t)t * KTOT + kt * 32;
            const uint4* sh = reinterpret_cast<const uint4*>(Bh_g + off);
            const uint4* sl = reinterpret_cast<const uint4*>(Bl_g + off);
            uint4 h0 = sh[0], h1 = sh[1], h2 = sh[2], h3 = sh[3];
            uint4 l0 = sl[0], l1 = sl[1], l2 = sl[2], l3 = sl[3];
            *reinterpret_cast<uint4*>(&Bhs[t][0])  = h0;
            *reinterpret_cast<uint4*>(&Bhs[t][8])  = h1;
            *reinterpret_cast<uint4*>(&Bhs[t][16]) = h2;
            *reinterpret_cast<uint4*>(&Bhs[t][24]) = h3;
            *reinterpret_cast<uint4*>(&Bls[t][0])  = l0;
            *reinterpret_cast<uint4*>(&Bls[t][8])  = l1;
            *reinterpret_cast<uint4*>(&Bls[t][16]) = l2;
            *reinterpret_cast<uint4*>(&Bls[t][24]) = l3;
        }
        __syncthreads();
        short8 ah[2], al[2];
#pragma unroll
        for (int m = 0; m < 2; m++) {
            int row = wr * 32 + m * 16 + l15;
            float av[8];
            *reinterpret_cast<float4*>(&av[0]) = *reinterpret_cast<const float4*>(&Xs[row][lg * 8]);
            *reinterpret_cast<float4*>(&av[4]) = *reinterpret_cast<const float4*>(&Xs[row][lg * 8 + 4]);
            split8(av, ah[m], al[m]);
        }
#pragma unroll
        for (int nr = 0; nr < 16; nr++) {
            int g = nr >> 2, nf = nr & 3;
            int n = g * 128 + wc * 64 + nf * 16 + l15;
            short8 bh = *reinterpret_cast<const short8*>(&Bhs[n][lg * 8]);
            short8 bl = *reinterpret_cast<const short8*>(&Bls[n][lg * 8]);
#pragma unroll
            for (int m = 0; m < 2; m++) {
                acc[m][nr] = __builtin_amdgcn_mfma_f32_16x16x32_bf16(ah[m], bh, acc[m][nr], 0, 0, 0);
                acc[m][nr] = __builtin_amdgcn_mfma_f32_16x16x32_bf16(ah[m], bl, acc[m][nr], 0, 0, 0);
                acc[m][nr] = __builtin_amdgcn_mfma_f32_16x16x32_bf16(al[m], bh, acc[m][nr], 0, 0, 0);
            }
        }
    }

    // activations + state update
#pragma unroll
    for (int m = 0; m < 2; m++)
#pragma unroll
        for (int rr = 0; rr < 4; rr++) {
            int gr = rb + wr * 32 + m * 16 + lg * 4 + rr;
            if (gr >= M) continue;
#pragma unroll
            for (int nf = 0; nf < 4; nf++) {
                int colc = wc * 64 + nf * 16 + l15;
                float gi = acc[m][nf][rr]      + bsum[colc];
                float gf = acc[m][4 + nf][rr]  + bsum[128 + colc];
                float gg = acc[m][8 + nf][rr]  + bsum[256 + colc];
                float go = acc[m][12 + nf][rr] + bsum[384 + colc];
                size_t p = (size_t)gr * 128 + colc;
                float cold = c_st[p];
                float cn = sigf(gf) * cold + sigf(gi) * tanhf(gg);
                float hn = sigf(go) * tanhf(cn);
                c_st[p] = cn;
                h_out[p] = hn;
            }
        }
}

// -------- scatter-add: out[sidx[e]+s_off] += msg[gidx[e]+g_off], 128 floats/row --------
__global__ __launch_bounds__(256) void scatter_add_k(
    const float* __restrict__ msg, const int* __restrict__ gidx, int g_off,
    const int* __restrict__ sidx, int s_off, float* __restrict__ out)
{
    int idx = blockIdx.x * 256 + threadIdx.x;
    int e = idx >> 5;
    if (e >= NE) return;
    int l = idx & 31;
    int rin = gidx[e] + g_off;
    int rout = sidx[e] + s_off;
    float4 v = *reinterpret_cast<const float4*>(msg + (size_t)rin * 128 + l * 4);
    float* op = out + (size_t)rout * 128 + l * 4;
    atomicAdd(op + 0, v.x);
    atomicAdd(op + 1, v.y);
    atomicAdd(op + 2, v.z);
    atomicAdd(op + 3, v.w);
}

extern "C" void kernel_launch(void* const* d_in, const int* in_sizes, int n_in,
                              void* d_out, int out_size, void* d_ws, size_t ws_size,
                              hipStream_t stream)
{
    const float* l_pos   = (const float*)d_in[0];
    const float* l_neg   = (const float*)d_in[1];
    const float* c_emb   = (const float*)d_in[2];
    const float* l_mlp_W = (const float*)d_in[3];
    const float* l_mlp_b = (const float*)d_in[4];
    const float* c_mlp_W = (const float*)d_in[5];
    const float* c_mlp_b = (const float*)d_in[6];
    const float* l_Wih   = (const float*)d_in[7];
    const float* l_Whh   = (const float*)d_in[8];
    const float* l_bih   = (const float*)d_in[9];
    const float* l_bhh   = (const float*)d_in[10];
    const float* c_Wih   = (const float*)d_in[11];
    const float* c_Whh   = (const float*)d_in[12];
    const float* c_bih   = (const float*)d_in[13];
    const float* c_bhh   = (const float*)d_in[14];
    const int* pos_src   = (const int*)d_in[15];
    const int* pos_dst   = (const int*)d_in[16];
    const int* neg_src   = (const int*)d_in[17];
    const int* neg_dst   = (const int*)d_in[18];

    float* out  = (float*)d_out;
    float* l_hA = out;
    float* c_h  = out + (size_t)NL * 128;

    float* wsp = (float*)d_ws;
    float* l_hB  = wsp; wsp += (size_t)NL * 128;
    float* l_c   = wsp; wsp += (size_t)NL * 128;
    float* c_c   = wsp; wsp += (size_t)NC * 128;
    float* l_msg = wsp; wsp += (size_t)NL * 128;
    float* c_msg = wsp; wsp += (size_t)NC * 128;
    float* l2c   = wsp; wsp += (size_t)NC * 128;
    float* c2l = l_msg;  // reused after l_msg consumed

    unsigned short* us = (unsigned short*)wsp;
    unsigned short* mlpLh = us; us += 3 * 128 * 128;
    unsigned short* mlpLl = us; us += 3 * 128 * 128;
    unsigned short* mlpCh = us; us += 3 * 128 * 128;
    unsigned short* mlpCl = us; us += 3 * 128 * 128;
    unsigned short* lstmLh = us; us += 512 * 384;
    unsigned short* lstmLl = us; us += 512 * 384;
    unsigned short* lstmCh = us; us += 512 * 256;
    unsigned short* lstmCl = us; us += 512 * 256;

    // init states
    hipMemcpyAsync(l_hA, l_pos, (size_t)NV * 128 * 4, hipMemcpyDeviceToDevice, stream);
    hipMemcpyAsync(l_hA + (size_t)NV * 128, l_neg, (size_t)NV * 128 * 4, hipMemcpyDeviceToDevice, stream);
    hipMemcpyAsync(c_h, c_emb, (size_t)NC * 128 * 4, hipMemcpyDeviceToDevice, stream);
    hipMemsetAsync(l_c, 0, (size_t)NL * 128 * 4, stream);
    hipMemsetAsync(c_c, 0, (size_t)NC * 128 * 4, stream);

    // pack weights (once per call)
    pack_mlp_k<<<192, 256, 0, stream>>>(l_mlp_W, mlpLh, mlpLl);
    pack_mlp_k<<<192, 256, 0, stream>>>(c_mlp_W, mlpCh, mlpCl);
    pack_lstm_k<<<768, 256, 0, stream>>>(l_Wih, l_Whh, 256, 384, lstmLh, lstmLl);
    pack_lstm_k<<<512, 256, 0, stream>>>(c_Wih, c_Whh, 128, 256, lstmCh, lstmCl);

    float* l_cur = l_hA;
    float* l_nxt = l_hB;

    for (int r = 0; r < NROUNDS; r++) {
        mlp3<<<(NL + 63) / 64, 256, 0, stream>>>(l_cur, mlpLh, mlpLl, l_mlp_b, l_msg, NL);
        mlp3<<<(NC + 63) / 64, 256, 0, stream>>>(c_h, mlpCh, mlpCl, c_mlp_b, c_msg, NC);

        hipMemsetAsync(l2c, 0, (size_t)NC * 128 * 4, stream);
        scatter_add_k<<<NE * 32 / 256, 256, 0, stream>>>(l_msg, pos_src, 0,  pos_dst, 0, l2c);
        scatter_add_k<<<NE * 32 / 256, 256, 0, stream>>>(l_msg, neg_src, NV, neg_dst, 0, l2c);
        hipMemsetAsync(c2l, 0, (size_t)NL * 128 * 4, stream);
        scatter_add_k<<<NE * 32 / 256, 256, 0, stream>>>(c_msg, pos_dst, 0, pos_src, 0,  c2l);
        scatter_add_k<<<NE * 32 / 256, 256, 0, stream>>>(c_msg, neg_dst, 0, neg_src, NV, c2l);

        lstm_mfma<12, true><<<(NL + 127) / 128, 512, 0, stream>>>(
            c2l, l_cur, l_cur, lstmLh, lstmLl, l_bih, l_bhh, l_c, l_nxt, NL);
        lstm_mfma<8, false><<<(NC + 127) / 128, 512, 0, stream>>>(
            l2c, c_h, nullptr, lstmCh, lstmCl, c_bih, c_bhh, c_c, c_h, NC);

        float* t2 = l_cur; l_cur = l_nxt; l_nxt = t2;
    }
    (void)in_sizes; (void)n_in; (void)out_size; (void)ws_size;
}

// Round 3
// 76306.250 us; speedup vs baseline: 1.5214x; 1.0523x over previous
//
#include <hip/hip_runtime.h>
#include <math.h>

typedef __attribute__((ext_vector_type(8))) short short8;
typedef __attribute__((ext_vector_type(4))) float f32x4;

constexpr int NV = 50000;    // V
constexpr int NL = 100000;   // 2V literal rows
constexpr int NC = 200000;   // clauses
constexpr int NE = 300000;   // edges per polarity
constexpr int NROUNDS = 26;

__device__ __forceinline__ float sigf(float x) { return 1.0f / (1.0f + expf(-x)); }

// in-register f32 -> bf16 hi/lo split (truncation; combined rel err ~2^-16)
__device__ __forceinline__ void split8(const float* a, short8& h, short8& l) {
#pragma unroll
    for (int j = 0; j < 8; j++) {
        unsigned u = __float_as_uint(a[j]);
        h[j] = (short)(u >> 16);
        float lf = a[j] - __uint_as_float(u & 0xffff0000u);
        l[j] = (short)(__float_as_uint(lf) >> 16);
    }
}

// weight split with RTN on both halves (one-time prep)
__device__ __forceinline__ void splitw(float x, unsigned short* h, unsigned short* l) {
    unsigned u = __float_as_uint(x);
    unsigned hr = (u + 0x7fffu + ((u >> 16) & 1u)) & 0xffff0000u;
    float lf = x - __uint_as_float(hr);
    unsigned ul = __float_as_uint(lf);
    *h = (unsigned short)(hr >> 16);
    *l = (unsigned short)((ul + 0x7fffu + ((ul >> 16) & 1u)) >> 16);
}

// ---- weight prep: MLP W[3][k][n] f32 -> WT[3][n][k] bf16 hi/lo ----
__global__ __launch_bounds__(256) void pack_mlp_k(
    const float* __restrict__ W, unsigned short* __restrict__ Wh, unsigned short* __restrict__ Wl)
{
    int idx = blockIdx.x * 256 + threadIdx.x;
    if (idx >= 3 * 128 * 128) return;
    int L = idx >> 14, r = idx & 16383, n = r >> 7, k = r & 127;
    splitw(W[(L << 14) + (k << 7) + n], &Wh[idx], &Wl[idx]);
}

// ---- weight prep: LSTM [Wih | Whh] -> BT[512][ktot] bf16 hi/lo (already [n][k]) ----
__global__ __launch_bounds__(256) void pack_lstm_k(
    const float* __restrict__ Wih, const float* __restrict__ Whh, int kih, int ktot,
    unsigned short* __restrict__ Wh, unsigned short* __restrict__ Wl)
{
    int idx = blockIdx.x * 256 + threadIdx.x;
    if (idx >= 512 * ktot) return;
    int n = idx / ktot, k = idx - n * ktot;
    float v = (k < kih) ? Wih[n * kih + k] : Whh[(n << 7) + (k - kih)];
    splitw(v, &Wh[idx], &Wl[idx]);
}

// ---------------- fused 3-layer MLP, bf16x3 MFMA ----------------
// block 256 (4 waves), BM=64; wave tile 32 rows x 64 cols (2x4 16x16 frags)
__global__ __launch_bounds__(256, 2) void mlp3(
    const float* __restrict__ x, const unsigned short* __restrict__ Wh,
    const unsigned short* __restrict__ Wl, const float* __restrict__ bias,
    float* __restrict__ y, int M)
{
    __shared__ float Xs[64][132];
    __shared__ unsigned short Bh[128][40];
    __shared__ unsigned short Bl[128][40];
    const int t = threadIdx.x;
    const int rb = blockIdx.x * 64;
    const int lane = t & 63, w = t >> 6, wr = w >> 1, wc = w & 1;
    const int l15 = lane & 15, lg = lane >> 4;

#pragma unroll
    for (int j = 0; j < 8; j++) {
        int i = t + 256 * j;
        int r = i >> 5, c4 = i & 31;
        int gr = rb + r; if (gr >= M) gr = M - 1;
        *reinterpret_cast<float4*>(&Xs[r][c4 * 4]) =
            *reinterpret_cast<const float4*>(x + (size_t)gr * 128 + c4 * 4);
    }

    for (int layer = 0; layer < 3; layer++) {
        f32x4 acc[2][4];
#pragma unroll
        for (int m = 0; m < 2; m++)
#pragma unroll
            for (int nf = 0; nf < 4; nf++) acc[m][nf] = f32x4{0.f, 0.f, 0.f, 0.f};

        for (int kt = 0; kt < 4; kt++) {
            __syncthreads();
            {   // stage B k-tile [128n][32k] hi/lo
                int n = t >> 1, kh = (t & 1) * 16;
                size_t off = (size_t)layer * 16384 + n * 128 + kt * 32 + kh;
                const uint4* sh = reinterpret_cast<const uint4*>(Wh + off);
                const uint4* sl = reinterpret_cast<const uint4*>(Wl + off);
                uint4 h0 = sh[0], h1 = sh[1], l0 = sl[0], l1 = sl[1];
                *reinterpret_cast<uint4*>(&Bh[n][kh]) = h0;
                *reinterpret_cast<uint4*>(&Bh[n][kh + 8]) = h1;
                *reinterpret_cast<uint4*>(&Bl[n][kh]) = l0;
                *reinterpret_cast<uint4*>(&Bl[n][kh + 8]) = l1;
            }
            __syncthreads();
            short8 bh[4], bl[4];
#pragma unroll
            for (int nf = 0; nf < 4; nf++) {
                int n = wc * 64 + nf * 16 + l15;
                bh[nf] = *reinterpret_cast<const short8*>(&Bh[n][lg * 8]);
                bl[nf] = *reinterpret_cast<const short8*>(&Bl[n][lg * 8]);
            }
#pragma unroll
            for (int m = 0; m < 2; m++) {
                int row = wr * 32 + m * 16 + l15;
                float av[8];
                *reinterpret_cast<float4*>(&av[0]) =
                    *reinterpret_cast<const float4*>(&Xs[row][kt * 32 + lg * 8]);
                *reinterpret_cast<float4*>(&av[4]) =
                    *reinterpret_cast<const float4*>(&Xs[row][kt * 32 + lg * 8 + 4]);
                short8 ah, al; split8(av, ah, al);
#pragma unroll
                for (int nf = 0; nf < 4; nf++) {
                    acc[m][nf] = __builtin_amdgcn_mfma_f32_16x16x32_bf16(ah, bh[nf], acc[m][nf], 0, 0, 0);
                    acc[m][nf] = __builtin_amdgcn_mfma_f32_16x16x32_bf16(ah, bl[nf], acc[m][nf], 0, 0, 0);
                    acc[m][nf] = __builtin_amdgcn_mfma_f32_16x16x32_bf16(al, bh[nf], acc[m][nf], 0, 0, 0);
                }
            }
        }
        __syncthreads();
        float bv[4];
#pragma unroll
        for (int nf = 0; nf < 4; nf++) bv[nf] = bias[layer * 128 + wc * 64 + nf * 16 + l15];
        if (layer < 2) {
#pragma unroll
            for (int m = 0; m < 2; m++)
#pragma unroll
                for (int nf = 0; nf < 4; nf++)
#pragma unroll
                    for (int rr = 0; rr < 4; rr++) {
                        float v = fmaxf(acc[m][nf][rr] + bv[nf], 0.f);
                        Xs[wr * 32 + m * 16 + lg * 4 + rr][wc * 64 + nf * 16 + l15] = v;
                    }
        } else {
#pragma unroll
            for (int m = 0; m < 2; m++)
#pragma unroll
                for (int rr = 0; rr < 4; rr++) {
                    int gr = rb + wr * 32 + m * 16 + lg * 4 + rr;
                    if (gr < M) {
#pragma unroll
                        for (int nf = 0; nf < 4; nf++)
                            y[(size_t)gr * 128 + wc * 64 + nf * 16 + l15] = acc[m][nf][rr] + bv[nf];
                    }
                }
        }
    }
}

// ---------------- fused LSTM (gates GEMM bf16x3 + activations) ----------------
// block 512 (8 waves), BM=128; wave tile 32 rows x 256 gate-cols (gate-grouped)
template <int NSTEP, bool FLIP>
__global__ __launch_bounds__(512, 2) void lstm_mfma(
    const float* __restrict__ A0, const float* __restrict__ A1, const float* __restrict__ A2,
    const unsigned short* __restrict__ Bh_g, const unsigned short* __restrict__ Bl_g,
    const float* __restrict__ bih, const float* __restrict__ bhh,
    float* __restrict__ c_st, float* __restrict__ h_out, int M)
{
    constexpr int KTOT = NSTEP * 32;
    __shared__ float Xs[128][36];
    __shared__ unsigned short Bhs[512][40];
    __shared__ unsigned short Bls[512][40];
    __shared__ float bsum[512];
    const int t = threadIdx.x;
    const int rb = blockIdx.x * 128;
    const int lane = t & 63, w = t >> 6, wr = w >> 1, wc = w & 1;
    const int l15 = lane & 15, lg = lane >> 4;
    bsum[t] = bih[t] + bhh[t];

    f32x4 acc[2][16];
#pragma unroll
    for (int m = 0; m < 2; m++)
#pragma unroll
        for (int nr = 0; nr < 16; nr++) acc[m][nr] = f32x4{0.f, 0.f, 0.f, 0.f};

    const int xrow = t >> 2, xc8 = (t & 3) * 8;
    int xgrow = rb + xrow; if (xgrow >= M) xgrow = M - 1;

    for (int kt = 0; kt < NSTEP; kt++) {
        __syncthreads();
        {   // stage X k-tile [128 rows][32 k] f32, segment-select
            int seg = kt >> 2;
            int kb = (kt & 3) * 32 + xc8;
            const float* src; size_t grow = (size_t)xgrow;
            if (NSTEP == 12) {
                if (seg == 0) src = A0;
                else if (seg == 1) {
                    src = A1;
                    if (FLIP) grow = (xgrow < NV) ? (size_t)(xgrow + NV) : (size_t)(xgrow - NV);
                } else src = A2;
            } else {
                src = seg ? A1 : A0;
            }
            const float4* sp = reinterpret_cast<const float4*>(src + grow * 128 + kb);
            float4 v0 = sp[0], v1 = sp[1];
            *reinterpret_cast<float4*>(&Xs[xrow][xc8]) = v0;
            *reinterpret_cast<float4*>(&Xs[xrow][xc8 + 4]) = v1;
        }
        {   // stage B k-tile [512n][32k] hi/lo
            size_t off = (size_t)t * KTOT + kt * 32;
            const uint4* sh = reinterpret_cast<const uint4*>(Bh_g + off);
            const uint4* sl = reinterpret_cast<const uint4*>(Bl_g + off);
            uint4 h0 = sh[0], h1 = sh[1], h2 = sh[2], h3 = sh[3];
            uint4 l0 = sl[0], l1 = sl[1], l2 = sl[2], l3 = sl[3];
            *reinterpret_cast<uint4*>(&Bhs[t][0])  = h0;
            *reinterpret_cast<uint4*>(&Bhs[t][8])  = h1;
            *reinterpret_cast<uint4*>(&Bhs[t][16]) = h2;
            *reinterpret_cast<uint4*>(&Bhs[t][24]) = h3;
            *reinterpret_cast<uint4*>(&Bls[t][0])  = l0;
            *reinterpret_cast<uint4*>(&Bls[t][8])  = l1;
            *reinterpret_cast<uint4*>(&Bls[t][16]) = l2;
            *reinterpret_cast<uint4*>(&Bls[t][24]) = l3;
        }
        __syncthreads();
        short8 ah[2], al[2];
#pragma unroll
        for (int m = 0; m < 2; m++) {
            int row = wr * 32 + m * 16 + l15;
            float av[8];
            *reinterpret_cast<float4*>(&av[0]) = *reinterpret_cast<const float4*>(&Xs[row][lg * 8]);
            *reinterpret_cast<float4*>(&av[4]) = *reinterpret_cast<const float4*>(&Xs[row][lg * 8 + 4]);
            split8(av, ah[m], al[m]);
        }
#pragma unroll
        for (int nr = 0; nr < 16; nr++) {
            int g = nr >> 2, nf = nr & 3;
            int n = g * 128 + wc * 64 + nf * 16 + l15;
            short8 bh = *reinterpret_cast<const short8*>(&Bhs[n][lg * 8]);
            short8 bl = *reinterpret_cast<const short8*>(&Bls[n][lg * 8]);
#pragma unroll
            for (int m = 0; m < 2; m++) {
                acc[m][nr] = __builtin_amdgcn_mfma_f32_16x16x32_bf16(ah[m], bh, acc[m][nr], 0, 0, 0);
                acc[m][nr] = __builtin_amdgcn_mfma_f32_16x16x32_bf16(ah[m], bl, acc[m][nr], 0, 0, 0);
                acc[m][nr] = __builtin_amdgcn_mfma_f32_16x16x32_bf16(al[m], bh, acc[m][nr], 0, 0, 0);
            }
        }
    }

    // activations + state update
#pragma unroll
    for (int m = 0; m < 2; m++)
#pragma unroll
        for (int rr = 0; rr < 4; rr++) {
            int gr = rb + wr * 32 + m * 16 + lg * 4 + rr;
            if (gr >= M) continue;
#pragma unroll
            for (int nf = 0; nf < 4; nf++) {
                int colc = wc * 64 + nf * 16 + l15;
                float gi = acc[m][nf][rr]      + bsum[colc];
                float gf = acc[m][4 + nf][rr]  + bsum[128 + colc];
                float gg = acc[m][8 + nf][rr]  + bsum[256 + colc];
                float go = acc[m][12 + nf][rr] + bsum[384 + colc];
                size_t p = (size_t)gr * 128 + colc;
                float cold = c_st[p];
                float cn = sigf(gf) * cold + sigf(gi) * tanhf(gg);
                float hn = sigf(go) * tanhf(cn);
                c_st[p] = cn;
                h_out[p] = hn;
            }
        }
}

// -------- scatter-add: out[sidx[e]+s_off] += msg[gidx[e]+g_off], 128 floats/row --------
__global__ __launch_bounds__(256) void scatter_add_k(
    const float* __restrict__ msg, const int* __restrict__ gidx, int g_off,
    const int* __restrict__ sidx, int s_off, float* __restrict__ out)
{
    int idx = blockIdx.x * 256 + threadIdx.x;
    int e = idx >> 5;
    if (e >= NE) return;
    int l = idx & 31;
    int rin = gidx[e] + g_off;
    int rout = sidx[e] + s_off;
    float4 v = *reinterpret_cast<const float4*>(msg + (size_t)rin * 128 + l * 4);
    float* op = out + (size_t)rout * 128 + l * 4;
    atomicAdd(op + 0, v.x);
    atomicAdd(op + 1, v.y);
    atomicAdd(op + 2, v.z);
    atomicAdd(op + 3, v.w);
}

extern "C" void kernel_launch(void* const* d_in, const int* in_sizes, int n_in,
                              void* d_out, int out_size, void* d_ws, size_t ws_size,
                              hipStream_t stream)
{
    const float* l_pos   = (const float*)d_in[0];
    const float* l_neg   = (const float*)d_in[1];
    const float* c_emb   = (const float*)d_in[2];
    const float* l_mlp_W = (const float*)d_in[3];
    const float* l_mlp_b = (const float*)d_in[4];
    const float* c_mlp_W = (const float*)d_in[5];
    const float* c_mlp_b = (const float*)d_in[6];
    const float* l_Wih   = (const float*)d_in[7];
    const float* l_Whh   = (const float*)d_in[8];
    const float* l_bih   = (const float*)d_in[9];
    const float* l_bhh   = (const float*)d_in[10];
    const float* c_Wih   = (const float*)d_in[11];
    const float* c_Whh   = (const float*)d_in[12];
    const float* c_bih   = (const float*)d_in[13];
    const float* c_bhh   = (const float*)d_in[14];
    const int* pos_src   = (const int*)d_in[15];
    const int* pos_dst   = (const int*)d_in[16];
    const int* neg_src   = (const int*)d_in[17];
    const int* neg_dst   = (const int*)d_in[18];

    float* out  = (float*)d_out;
    float* l_hA = out;
    float* c_h  = out + (size_t)NL * 128;

    float* wsp = (float*)d_ws;
    float* l_hB  = wsp; wsp += (size_t)NL * 128;
    float* l_c   = wsp; wsp += (size_t)NL * 128;
    float* c_c   = wsp; wsp += (size_t)NC * 128;
    float* l_msg = wsp; wsp += (size_t)NL * 128;
    float* c_msg = wsp; wsp += (size_t)NC * 128;
    float* l2c   = wsp; wsp += (size_t)NC * 128;
    float* c2l = l_msg;  // reused after l_msg consumed

    unsigned short* us = (unsigned short*)wsp;
    unsigned short* mlpLh = us; us += 3 * 128 * 128;
    unsigned short* mlpLl = us; us += 3 * 128 * 128;
    unsigned short* mlpCh = us; us += 3 * 128 * 128;
    unsigned short* mlpCl = us; us += 3 * 128 * 128;
    unsigned short* lstmLh = us; us += 512 * 384;
    unsigned short* lstmLl = us; us += 512 * 384;
    unsigned short* lstmCh = us; us += 512 * 256;
    unsigned short* lstmCl = us; us += 512 * 256;

    // init states
    hipMemcpyAsync(l_hA, l_pos, (size_t)NV * 128 * 4, hipMemcpyDeviceToDevice, stream);
    hipMemcpyAsync(l_hA + (size_t)NV * 128, l_neg, (size_t)NV * 128 * 4, hipMemcpyDeviceToDevice, stream);
    hipMemcpyAsync(c_h, c_emb, (size_t)NC * 128 * 4, hipMemcpyDeviceToDevice, stream);
    hipMemsetAsync(l_c, 0, (size_t)NL * 128 * 4, stream);
    hipMemsetAsync(c_c, 0, (size_t)NC * 128 * 4, stream);

    // pack weights (once per call)
    pack_mlp_k<<<192, 256, 0, stream>>>(l_mlp_W, mlpLh, mlpLl);
    pack_mlp_k<<<192, 256, 0, stream>>>(c_mlp_W, mlpCh, mlpCl);
    pack_lstm_k<<<768, 256, 0, stream>>>(l_Wih, l_Whh, 256, 384, lstmLh, lstmLl);
    pack_lstm_k<<<512, 256, 0, stream>>>(c_Wih, c_Whh, 128, 256, lstmCh, lstmCl);

    float* l_cur = l_hA;
    float* l_nxt = l_hB;

    for (int r = 0; r < NROUNDS; r++) {
        mlp3<<<(NL + 63) / 64, 256, 0, stream>>>(l_cur, mlpLh, mlpLl, l_mlp_b, l_msg, NL);
        mlp3<<<(NC + 63) / 64, 256, 0, stream>>>(c_h, mlpCh, mlpCl, c_mlp_b, c_msg, NC);

        hipMemsetAsync(l2c, 0, (size_t)NC * 128 * 4, stream);
        scatter_add_k<<<NE * 32 / 256, 256, 0, stream>>>(l_msg, pos_src, 0,  pos_dst, 0, l2c);
        scatter_add_k<<<NE * 32 / 256, 256, 0, stream>>>(l_msg, neg_src, NV, neg_dst, 0, l2c);
        hipMemsetAsync(c2l, 0, (size_t)NL * 128 * 4, stream);
        scatter_add_k<<<NE * 32 / 256, 256, 0, stream>>>(c_msg, pos_dst, 0, pos_src, 0,  c2l);
        scatter_add_k<<<NE * 32 / 256, 256, 0, stream>>>(c_msg, neg_dst, 0, neg_src, NV, c2l);

        lstm_mfma<12, true><<<(NL + 127) / 128, 512, 0, stream>>>(
            c2l, l_cur, l_cur, lstmLh, lstmLl, l_bih, l_bhh, l_c, l_nxt, NL);
        lstm_mfma<8, false><<<(NC + 127) / 128, 512, 0, stream>>>(
            l2c, c_h, nullptr, lstmCh, lstmCl, c_bih, c_bhh, c_c, c_h, NC);

        float* t2 = l_cur; l_cur = l_nxt; l_nxt = t2;
    }
    (void)in_sizes; (void)n_in; (void)out_size; (void)ws_size;
}

// Round 4
// 76287.256 us; speedup vs baseline: 1.5218x; 1.0002x over previous
//
#include <hip/hip_runtime.h>
#include <math.h>

typedef __attribute__((ext_vector_type(8))) short short8;
typedef __attribute__((ext_vector_type(4))) float f32x4;

constexpr int NV = 50000;    // V
constexpr int NL = 100000;   // 2V literal rows
constexpr int NC = 200000;   // clauses
constexpr int NE = 300000;   // edges per polarity
constexpr int NROUNDS = 26;

__device__ __forceinline__ float sigf(float x) { return 1.0f / (1.0f + expf(-x)); }

// in-register f32 -> bf16 hi/lo split (truncation; combined rel err ~2^-16)
__device__ __forceinline__ void split8(const float* a, short8& h, short8& l) {
#pragma unroll
    for (int j = 0; j < 8; j++) {
        unsigned u = __float_as_uint(a[j]);
        h[j] = (short)(u >> 16);
        float lf = a[j] - __uint_as_float(u & 0xffff0000u);
        l[j] = (short)(__float_as_uint(lf) >> 16);
    }
}

// weight split with RTN on both halves (one-time prep)
__device__ __forceinline__ void splitw(float x, unsigned short* h, unsigned short* l) {
    unsigned u = __float_as_uint(x);
    unsigned hr = (u + 0x7fffu + ((u >> 16) & 1u)) & 0xffff0000u;
    float lf = x - __uint_as_float(hr);
    unsigned ul = __float_as_uint(lf);
    *h = (unsigned short)(hr >> 16);
    *l = (unsigned short)((ul + 0x7fffu + ((ul >> 16) & 1u)) >> 16);
}

// ---- weight prep: MLP W[3][k][n] f32 -> WT[3][n][k] bf16 hi/lo ----
__global__ __launch_bounds__(256) void pack_mlp_k(
    const float* __restrict__ W, unsigned short* __restrict__ Wh, unsigned short* __restrict__ Wl)
{
    int idx = blockIdx.x * 256 + threadIdx.x;
    if (idx >= 3 * 128 * 128) return;
    int L = idx >> 14, r = idx & 16383, n = r >> 7, k = r & 127;
    splitw(W[(L << 14) + (k << 7) + n], &Wh[idx], &Wl[idx]);
}

// ---- weight prep: LSTM [Wih | Whh] -> BT[512][ktot] bf16 hi/lo (already [n][k]) ----
__global__ __launch_bounds__(256) void pack_lstm_k(
    const float* __restrict__ Wih, const float* __restrict__ Whh, int kih, int ktot,
    unsigned short* __restrict__ Wh, unsigned short* __restrict__ Wl)
{
    int idx = blockIdx.x * 256 + threadIdx.x;
    if (idx >= 512 * ktot) return;
    int n = idx / ktot, k = idx - n * ktot;
    float v = (k < kih) ? Wih[n * kih + k] : Whh[(n << 7) + (k - kih)];
    splitw(v, &Wh[idx], &Wl[idx]);
}

// ---------------- fused 3-layer MLP, bf16x3 MFMA ----------------
// block 256 (4 waves), BM=64; wave tile 32 rows x 64 cols (2x4 16x16 frags)
__global__ __launch_bounds__(256, 2) void mlp3(
    const float* __restrict__ x, const unsigned short* __restrict__ Wh,
    const unsigned short* __restrict__ Wl, const float* __restrict__ bias,
    float* __restrict__ y, int M)
{
    __shared__ float Xs[64][132];
    __shared__ unsigned short Bh[128][40];
    __shared__ unsigned short Bl[128][40];
    const int t = threadIdx.x;
    const int rb = blockIdx.x * 64;
    const int lane = t & 63, w = t >> 6, wr = w >> 1, wc = w & 1;
    const int l15 = lane & 15, lg = lane >> 4;

#pragma unroll
    for (int j = 0; j < 8; j++) {
        int i = t + 256 * j;
        int r = i >> 5, c4 = i & 31;
        int gr = rb + r; if (gr >= M) gr = M - 1;
        *reinterpret_cast<float4*>(&Xs[r][c4 * 4]) =
            *reinterpret_cast<const float4*>(x + (size_t)gr * 128 + c4 * 4);
    }

    for (int layer = 0; layer < 3; layer++) {
        f32x4 acc[2][4];
#pragma unroll
        for (int m = 0; m < 2; m++)
#pragma unroll
            for (int nf = 0; nf < 4; nf++) acc[m][nf] = f32x4{0.f, 0.f, 0.f, 0.f};

        for (int kt = 0; kt < 4; kt++) {
            __syncthreads();
            {   // stage B k-tile [128n][32k] hi/lo
                int n = t >> 1, kh = (t & 1) * 16;
                size_t off = (size_t)layer * 16384 + n * 128 + kt * 32 + kh;
                const uint4* sh = reinterpret_cast<const uint4*>(Wh + off);
                const uint4* sl = reinterpret_cast<const uint4*>(Wl + off);
                uint4 h0 = sh[0], h1 = sh[1], l0 = sl[0], l1 = sl[1];
                *reinterpret_cast<uint4*>(&Bh[n][kh]) = h0;
                *reinterpret_cast<uint4*>(&Bh[n][kh + 8]) = h1;
                *reinterpret_cast<uint4*>(&Bl[n][kh]) = l0;
                *reinterpret_cast<uint4*>(&Bl[n][kh + 8]) = l1;
            }
            __syncthreads();
            short8 bh[4], bl[4];
#pragma unroll
            for (int nf = 0; nf < 4; nf++) {
                int n = wc * 64 + nf * 16 + l15;
                bh[nf] = *reinterpret_cast<const short8*>(&Bh[n][lg * 8]);
                bl[nf] = *reinterpret_cast<const short8*>(&Bl[n][lg * 8]);
            }
#pragma unroll
            for (int m = 0; m < 2; m++) {
                int row = wr * 32 + m * 16 + l15;
                float av[8];
                *reinterpret_cast<float4*>(&av[0]) =
                    *reinterpret_cast<const float4*>(&Xs[row][kt * 32 + lg * 8]);
                *reinterpret_cast<float4*>(&av[4]) =
                    *reinterpret_cast<const float4*>(&Xs[row][kt * 32 + lg * 8 + 4]);
                short8 ah, al; split8(av, ah, al);
#pragma unroll
                for (int nf = 0; nf < 4; nf++) {
                    acc[m][nf] = __builtin_amdgcn_mfma_f32_16x16x32_bf16(ah, bh[nf], acc[m][nf], 0, 0, 0);
                    acc[m][nf] = __builtin_amdgcn_mfma_f32_16x16x32_bf16(ah, bl[nf], acc[m][nf], 0, 0, 0);
                    acc[m][nf] = __builtin_amdgcn_mfma_f32_16x16x32_bf16(al, bh[nf], acc[m][nf], 0, 0, 0);
                }
            }
        }
        __syncthreads();
        float bv[4];
#pragma unroll
        for (int nf = 0; nf < 4; nf++) bv[nf] = bias[layer * 128 + wc * 64 + nf * 16 + l15];
        if (layer < 2) {
#pragma unroll
            for (int m = 0; m < 2; m++)
#pragma unroll
                for (int nf = 0; nf < 4; nf++)
#pragma unroll
                    for (int rr = 0; rr < 4; rr++) {
                        float v = fmaxf(acc[m][nf][rr] + bv[nf], 0.f);
                        Xs[wr * 32 + m * 16 + lg * 4 + rr][wc * 64 + nf * 16 + l15] = v;
                    }
        } else {
#pragma unroll
            for (int m = 0; m < 2; m++)
#pragma unroll
                for (int rr = 0; rr < 4; rr++) {
                    int gr = rb + wr * 32 + m * 16 + lg * 4 + rr;
                    if (gr < M) {
#pragma unroll
                        for (int nf = 0; nf < 4; nf++)
                            y[(size_t)gr * 128 + wc * 64 + nf * 16 + l15] = acc[m][nf][rr] + bv[nf];
                    }
                }
        }
    }
}

// ---------------- fused LSTM (gates GEMM bf16x3 + activations) ----------------
// block 512 (8 waves), BM=128; wave tile 32 rows x 256 gate-cols (gate-grouped)
template <int NSTEP, bool FLIP>
__global__ __launch_bounds__(512, 2) void lstm_mfma(
    const float* __restrict__ A0, const float* __restrict__ A1, const float* __restrict__ A2,
    const unsigned short* __restrict__ Bh_g, const unsigned short* __restrict__ Bl_g,
    const float* __restrict__ bih, const float* __restrict__ bhh,
    float* __restrict__ c_st, float* __restrict__ h_out, int M)
{
    constexpr int KTOT = NSTEP * 32;
    __shared__ float Xs[128][36];
    __shared__ unsigned short Bhs[512][40];
    __shared__ unsigned short Bls[512][40];
    __shared__ float bsum[512];
    const int t = threadIdx.x;
    const int rb = blockIdx.x * 128;
    const int lane = t & 63, w = t >> 6, wr = w >> 1, wc = w & 1;
    const int l15 = lane & 15, lg = lane >> 4;
    bsum[t] = bih[t] + bhh[t];

    f32x4 acc[2][16];
#pragma unroll
    for (int m = 0; m < 2; m++)
#pragma unroll
        for (int nr = 0; nr < 16; nr++) acc[m][nr] = f32x4{0.f, 0.f, 0.f, 0.f};

    const int xrow = t >> 2, xc8 = (t & 3) * 8;
    int xgrow = rb + xrow; if (xgrow >= M) xgrow = M - 1;

    for (int kt = 0; kt < NSTEP; kt++) {
        __syncthreads();
        {   // stage X k-tile [128 rows][32 k] f32, segment-select
            int seg = kt >> 2;
            int kb = (kt & 3) * 32 + xc8;
            const float* src; size_t grow = (size_t)xgrow;
            if (NSTEP == 12) {
                if (seg == 0) src = A0;
                else if (seg == 1) {
                    src = A1;
                    if (FLIP) grow = (xgrow < NV) ? (size_t)(xgrow + NV) : (size_t)(xgrow - NV);
                } else src = A2;
            } else {
                src = seg ? A1 : A0;
            }
            const float4* sp = reinterpret_cast<const float4*>(src + grow * 128 + kb);
            float4 v0 = sp[0], v1 = sp[1];
            *reinterpret_cast<float4*>(&Xs[xrow][xc8]) = v0;
            *reinterpret_cast<float4*>(&Xs[xrow][xc8 + 4]) = v1;
        }
        {   // stage B k-tile [512n][32k] hi/lo
            size_t off = (size_t)t * KTOT + kt * 32;
            const uint4* sh = reinterpret_cast<const uint4*>(Bh_g + off);
            const uint4* sl = reinterpret_cast<const uint4*>(Bl_g + off);
            uint4 h0 = sh[0], h1 = sh[1], h2 = sh[2], h3 = sh[3];
            uint4 l0 = sl[0], l1 = sl[1], l2 = sl[2], l3 = sl[3];
            *reinterpret_cast<uint4*>(&Bhs[t][0])  = h0;
            *reinterpret_cast<uint4*>(&Bhs[t][8])  = h1;
            *reinterpret_cast<uint4*>(&Bhs[t][16]) = h2;
            *reinterpret_cast<uint4*>(&Bhs[t][24]) = h3;
            *reinterpret_cast<uint4*>(&Bls[t][0])  = l0;
            *reinterpret_cast<uint4*>(&Bls[t][8])  = l1;
            *reinterpret_cast<uint4*>(&Bls[t][16]) = l2;
            *reinterpret_cast<uint4*>(&Bls[t][24]) = l3;
        }
        __syncthreads();
        short8 ah[2], al[2];
#pragma unroll
        for (int m = 0; m < 2; m++) {
            int row = wr * 32 + m * 16 + l15;
            float av[8];
            *reinterpret_cast<float4*>(&av[0]) = *reinterpret_cast<const float4*>(&Xs[row][lg * 8]);
            *reinterpret_cast<float4*>(&av[4]) = *reinterpret_cast<const float4*>(&Xs[row][lg * 8 + 4]);
            split8(av, ah[m], al[m]);
        }
#pragma unroll
        for (int nr = 0; nr < 16; nr++) {
            int g = nr >> 2, nf = nr & 3;
            int n = g * 128 + wc * 64 + nf * 16 + l15;
            short8 bh = *reinterpret_cast<const short8*>(&Bhs[n][lg * 8]);
            short8 bl = *reinterpret_cast<const short8*>(&Bls[n][lg * 8]);
#pragma unroll
            for (int m = 0; m < 2; m++) {
                acc[m][nr] = __builtin_amdgcn_mfma_f32_16x16x32_bf16(ah[m], bh, acc[m][nr], 0, 0, 0);
                acc[m][nr] = __builtin_amdgcn_mfma_f32_16x16x32_bf16(ah[m], bl, acc[m][nr], 0, 0, 0);
                acc[m][nr] = __builtin_amdgcn_mfma_f32_16x16x32_bf16(al[m], bh, acc[m][nr], 0, 0, 0);
            }
        }
    }

    // activations + state update
#pragma unroll
    for (int m = 0; m < 2; m++)
#pragma unroll
        for (int rr = 0; rr < 4; rr++) {
            int gr = rb + wr * 32 + m * 16 + lg * 4 + rr;
            if (gr >= M) continue;
#pragma unroll
            for (int nf = 0; nf < 4; nf++) {
                int colc = wc * 64 + nf * 16 + l15;
                float gi = acc[m][nf][rr]      + bsum[colc];
                float gf = acc[m][4 + nf][rr]  + bsum[128 + colc];
                float gg = acc[m][8 + nf][rr]  + bsum[256 + colc];
                float go = acc[m][12 + nf][rr] + bsum[384 + colc];
                size_t p = (size_t)gr * 128 + colc;
                float cold = c_st[p];
                float cn = sigf(gf) * cold + sigf(gi) * tanhf(gg);
                float hn = sigf(go) * tanhf(cn);
                c_st[p] = cn;
                h_out[p] = hn;
            }
        }
}

// -------- scatter-add: out[sidx[e]+s_off] += msg[gidx[e]+g_off], 128 floats/row --------
__global__ __launch_bounds__(256) void scatter_add_k(
    const float* __restrict__ msg, const int* __restrict__ gidx, int g_off,
    const int* __restrict__ sidx, int s_off, float* __restrict__ out)
{
    int idx = blockIdx.x * 256 + threadIdx.x;
    int e = idx >> 5;
    if (e >= NE) return;
    int l = idx & 31;
    int rin = gidx[e] + g_off;
    int rout = sidx[e] + s_off;
    float4 v = *reinterpret_cast<const float4*>(msg + (size_t)rin * 128 + l * 4);
    float* op = out + (size_t)rout * 128 + l * 4;
    atomicAdd(op + 0, v.x);
    atomicAdd(op + 1, v.y);
    atomicAdd(op + 2, v.z);
    atomicAdd(op + 3, v.w);
}

extern "C" void kernel_launch(void* const* d_in, const int* in_sizes, int n_in,
                              void* d_out, int out_size, void* d_ws, size_t ws_size,
                              hipStream_t stream)
{
    const float* l_pos   = (const float*)d_in[0];
    const float* l_neg   = (const float*)d_in[1];
    const float* c_emb   = (const float*)d_in[2];
    const float* l_mlp_W = (const float*)d_in[3];
    const float* l_mlp_b = (const float*)d_in[4];
    const float* c_mlp_W = (const float*)d_in[5];
    const float* c_mlp_b = (const float*)d_in[6];
    const float* l_Wih   = (const float*)d_in[7];
    const float* l_Whh   = (const float*)d_in[8];
    const float* l_bih   = (const float*)d_in[9];
    const float* l_bhh   = (const float*)d_in[10];
    const float* c_Wih   = (const float*)d_in[11];
    const float* c_Whh   = (const float*)d_in[12];
    const float* c_bih   = (const float*)d_in[13];
    const float* c_bhh   = (const float*)d_in[14];
    const int* pos_src   = (const int*)d_in[15];
    const int* pos_dst   = (const int*)d_in[16];
    const int* neg_src   = (const int*)d_in[17];
    const int* neg_dst   = (const int*)d_in[18];

    float* out  = (float*)d_out;
    float* l_hA = out;
    float* c_h  = out + (size_t)NL * 128;

    float* wsp = (float*)d_ws;
    float* l_hB  = wsp; wsp += (size_t)NL * 128;
    float* l_c   = wsp; wsp += (size_t)NL * 128;
    float* c_c   = wsp; wsp += (size_t)NC * 128;
    float* l_msg = wsp; wsp += (size_t)NL * 128;
    float* c_msg = wsp; wsp += (size_t)NC * 128;
    float* l2c   = wsp; wsp += (size_t)NC * 128;
    float* c2l = l_msg;  // reused after l_msg consumed

    unsigned short* us = (unsigned short*)wsp;
    unsigned short* mlpLh = us; us += 3 * 128 * 128;
    unsigned short* mlpLl = us; us += 3 * 128 * 128;
    unsigned short* mlpCh = us; us += 3 * 128 * 128;
    unsigned short* mlpCl = us; us += 3 * 128 * 128;
    unsigned short* lstmLh = us; us += 512 * 384;
    unsigned short* lstmLl = us; us += 512 * 384;
    unsigned short* lstmCh = us; us += 512 * 256;
    unsigned short* lstmCl = us; us += 512 * 256;

    // init states
    hipMemcpyAsync(l_hA, l_pos, (size_t)NV * 128 * 4, hipMemcpyDeviceToDevice, stream);
    hipMemcpyAsync(l_hA + (size_t)NV * 128, l_neg, (size_t)NV * 128 * 4, hipMemcpyDeviceToDevice, stream);
    hipMemcpyAsync(c_h, c_emb, (size_t)NC * 128 * 4, hipMemcpyDeviceToDevice, stream);
    hipMemsetAsync(l_c, 0, (size_t)NL * 128 * 4, stream);
    hipMemsetAsync(c_c, 0, (size_t)NC * 128 * 4, stream);

    // pack weights (once per call)
    pack_mlp_k<<<192, 256, 0, stream>>>(l_mlp_W, mlpLh, mlpLl);
    pack_mlp_k<<<192, 256, 0, stream>>>(c_mlp_W, mlpCh, mlpCl);
    pack_lstm_k<<<768, 256, 0, stream>>>(l_Wih, l_Whh, 256, 384, lstmLh, lstmLl);
    pack_lstm_k<<<512, 256, 0, stream>>>(c_Wih, c_Whh, 128, 256, lstmCh, lstmCl);

    float* l_cur = l_hA;
    float* l_nxt = l_hB;

    for (int r = 0; r < NROUNDS; r++) {
        mlp3<<<(NL + 63) / 64, 256, 0, stream>>>(l_cur, mlpLh, mlpLl, l_mlp_b, l_msg, NL);
        mlp3<<<(NC + 63) / 64, 256, 0, stream>>>(c_h, mlpCh, mlpCl, c_mlp_b, c_msg, NC);

        hipMemsetAsync(l2c, 0, (size_t)NC * 128 * 4, stream);
        scatter_add_k<<<NE * 32 / 256, 256, 0, stream>>>(l_msg, pos_src, 0,  pos_dst, 0, l2c);
        scatter_add_k<<<NE * 32 / 256, 256, 0, stream>>>(l_msg, neg_src, NV, neg_dst, 0, l2c);
        hipMemsetAsync(c2l, 0, (size_t)NL * 128 * 4, stream);
        scatter_add_k<<<NE * 32 / 256, 256, 0, stream>>>(c_msg, pos_dst, 0, pos_src, 0,  c2l);
        scatter_add_k<<<NE * 32 / 256, 256, 0, stream>>>(c_msg, neg_dst, 0, neg_src, NV, c2l);

        lstm_mfma<12, true><<<(NL + 127) / 128, 512, 0, stream>>>(
            c2l, l_cur, l_cur, lstmLh, lstmLl, l_bih, l_bhh, l_c, l_nxt, NL);
        lstm_mfma<8, false><<<(NC + 127) / 128, 512, 0, stream>>>(
            l2c, c_h, nullptr, lstmCh, lstmCl, c_bih, c_bhh, c_c, c_h, NC);

        float* t2 = l_cur; l_cur = l_nxt; l_nxt = t2;
    }
    (void)in_sizes; (void)n_in; (void)out_size; (void)ws_size;
}

// Round 5
// 27324.725 us; speedup vs baseline: 4.2485x; 2.7919x over previous
//
#include <hip/hip_runtime.h>
#include <math.h>

typedef __attribute__((ext_vector_type(8))) short short8;
typedef __attribute__((ext_vector_type(4))) float f32x4;

constexpr int NV = 50000;    // V
constexpr int NL = 100000;   // 2V literal rows
constexpr int NC = 200000;   // clauses
constexpr int NE = 300000;   // edges per polarity
constexpr int NROUNDS = 26;

__device__ __forceinline__ float sigf(float x) { return 1.0f / (1.0f + expf(-x)); }

// in-register f32 -> bf16 hi/lo split (truncation; combined rel err ~2^-16)
__device__ __forceinline__ void split8(const float* a, short8& h, short8& l) {
#pragma unroll
    for (int j = 0; j < 8; j++) {
        unsigned u = __float_as_uint(a[j]);
        h[j] = (short)(u >> 16);
        float lf = a[j] - __uint_as_float(u & 0xffff0000u);
        l[j] = (short)(__float_as_uint(lf) >> 16);
    }
}

// weight split with RTN on both halves (one-time prep)
__device__ __forceinline__ void splitw(float x, unsigned short* h, unsigned short* l) {
    unsigned u = __float_as_uint(x);
    unsigned hr = (u + 0x7fffu + ((u >> 16) & 1u)) & 0xffff0000u;
    float lf = x - __uint_as_float(hr);
    unsigned ul = __float_as_uint(lf);
    *h = (unsigned short)(hr >> 16);
    *l = (unsigned short)((ul + 0x7fffu + ((ul >> 16) & 1u)) >> 16);
}

// ---- weight prep: MLP W[3][k][n] f32 -> WT[3][n][k] bf16 hi/lo ----
__global__ __launch_bounds__(256) void pack_mlp_k(
    const float* __restrict__ W, unsigned short* __restrict__ Wh, unsigned short* __restrict__ Wl)
{
    int idx = blockIdx.x * 256 + threadIdx.x;
    if (idx >= 3 * 128 * 128) return;
    int L = idx >> 14, r = idx & 16383, n = r >> 7, k = r & 127;
    splitw(W[(L << 14) + (k << 7) + n], &Wh[idx], &Wl[idx]);
}

// ---- weight prep: LSTM [Wih | Whh] -> BT[512][ktot] bf16 hi/lo (already [n][k]) ----
__global__ __launch_bounds__(256) void pack_lstm_k(
    const float* __restrict__ Wih, const float* __restrict__ Whh, int kih, int ktot,
    unsigned short* __restrict__ Wh, unsigned short* __restrict__ Wl)
{
    int idx = blockIdx.x * 256 + threadIdx.x;
    if (idx >= 512 * ktot) return;
    int n = idx / ktot, k = idx - n * ktot;
    float v = (k < kih) ? Wih[n * kih + k] : Whh[(n << 7) + (k - kih)];
    splitw(v, &Wh[idx], &Wl[idx]);
}

// ================= CSR build (once per call; graph is static across rounds) =================
__global__ __launch_bounds__(256) void csr_hist_k(
    const int* __restrict__ ps, const int* __restrict__ pd,
    const int* __restrict__ ns, const int* __restrict__ nd,
    int* __restrict__ cnt_c, int* __restrict__ cnt_l)
{
    int e = blockIdx.x * 256 + threadIdx.x;
    if (e >= NE) return;
    atomicAdd(&cnt_c[pd[e]], 1);
    atomicAdd(&cnt_c[nd[e]], 1);
    atomicAdd(&cnt_l[ps[e]], 1);
    atomicAdd(&cnt_l[NV + ns[e]], 1);
}

__global__ __launch_bounds__(256) void scan_p1(
    const int* __restrict__ cnt, int* __restrict__ partials, int n)
{
    __shared__ int sdata[256];
    int t = threadIdx.x, b = blockIdx.x;
    int base = b * 1024 + t * 4;
    int s = 0;
#pragma unroll
    for (int j = 0; j < 4; j++) { int i = base + j; if (i < n) s += cnt[i]; }
    sdata[t] = s; __syncthreads();
    for (int st = 128; st > 0; st >>= 1) {
        if (t < st) sdata[t] += sdata[t + st];
        __syncthreads();
    }
    if (t == 0) partials[b] = sdata[0];
}

// single block: exclusive-scan partials (nb <= 256), write total to *rowptr_end
__global__ __launch_bounds__(256) void scan_p2(int* __restrict__ partials, int nb, int* __restrict__ rowptr_end)
{
    __shared__ int sdata[256];
    int t = threadIdx.x;
    int v = (t < nb) ? partials[t] : 0;
    int x = v;
    sdata[t] = x; __syncthreads();
    for (int st = 1; st < 256; st <<= 1) {
        int y = (t >= st) ? sdata[t - st] : 0;
        __syncthreads();
        x += y; sdata[t] = x;
        __syncthreads();
    }
    if (t < nb) partials[t] = x - v;
    if (t == 255) *rowptr_end = sdata[255];
}

__global__ __launch_bounds__(256) void scan_p3(
    const int* __restrict__ cnt, const int* __restrict__ partials,
    int* __restrict__ rowptr, int* __restrict__ cursor, int n)
{
    __shared__ int sdata[256];
    int t = threadIdx.x, b = blockIdx.x;
    int base = b * 1024 + t * 4;
    int v[4]; int s = 0;
#pragma unroll
    for (int j = 0; j < 4; j++) { int i = base + j; v[j] = (i < n) ? cnt[i] : 0; s += v[j]; }
    int x = s;
    sdata[t] = x; __syncthreads();
    for (int st = 1; st < 256; st <<= 1) {
        int y = (t >= st) ? sdata[t - st] : 0;
        __syncthreads();
        x += y; sdata[t] = x;
        __syncthreads();
    }
    int off = partials[b] + x - s;
#pragma unroll
    for (int j = 0; j < 4; j++) {
        int i = base + j;
        if (i < n) { rowptr[i] = off; cursor[i] = off; off += v[j]; }
    }
}

__global__ __launch_bounds__(256) void csr_fill_k(
    const int* __restrict__ ps, const int* __restrict__ pd,
    const int* __restrict__ ns, const int* __restrict__ nd,
    int* __restrict__ cur_c, int* __restrict__ eidx_c,
    int* __restrict__ cur_l, int* __restrict__ eidx_l)
{
    int e = blockIdx.x * 256 + threadIdx.x;
    if (e >= NE) return;
    int p;
    p = atomicAdd(&cur_c[pd[e]], 1); eidx_c[p] = ps[e];
    p = atomicAdd(&cur_c[nd[e]], 1); eidx_c[p] = NV + ns[e];
    p = atomicAdd(&cur_l[ps[e]], 1); eidx_l[p] = pd[e];
    p = atomicAdd(&cur_l[NV + ns[e]], 1); eidx_l[p] = nd[e];
}

// ---- gather-sum: out[row] = sum_{j in [rowptr[row],rowptr[row+1])} msg[eidx[j]] ----
// one wave per row; lane holds float2 of the 128-wide feature
__global__ __launch_bounds__(256) void gather_sum_k(
    const float* __restrict__ msg, const int* __restrict__ rowptr,
    const int* __restrict__ eidx, float* __restrict__ out, int nrows)
{
    int row = (blockIdx.x * 256 + threadIdx.x) >> 6;
    if (row >= nrows) return;
    int lane = threadIdx.x & 63;
    int beg = rowptr[row], end = rowptr[row + 1];
    float ax = 0.f, ay = 0.f;
    for (int j = beg; j < end; j++) {
        int src = eidx[j];
        float2 v = *reinterpret_cast<const float2*>(msg + (size_t)src * 128 + lane * 2);
        ax += v.x; ay += v.y;
    }
    *reinterpret_cast<float2*>(out + (size_t)row * 128 + lane * 2) = make_float2(ax, ay);
}

// ---------------- fused 3-layer MLP, bf16x3 MFMA ----------------
__global__ __launch_bounds__(256, 2) void mlp3(
    const float* __restrict__ x, const unsigned short* __restrict__ Wh,
    const unsigned short* __restrict__ Wl, const float* __restrict__ bias,
    float* __restrict__ y, int M)
{
    __shared__ float Xs[64][132];
    __shared__ unsigned short Bh[128][40];
    __shared__ unsigned short Bl[128][40];
    const int t = threadIdx.x;
    const int rb = blockIdx.x * 64;
    const int lane = t & 63, w = t >> 6, wr = w >> 1, wc = w & 1;
    const int l15 = lane & 15, lg = lane >> 4;

#pragma unroll
    for (int j = 0; j < 8; j++) {
        int i = t + 256 * j;
        int r = i >> 5, c4 = i & 31;
        int gr = rb + r; if (gr >= M) gr = M - 1;
        *reinterpret_cast<float4*>(&Xs[r][c4 * 4]) =
            *reinterpret_cast<const float4*>(x + (size_t)gr * 128 + c4 * 4);
    }

    for (int layer = 0; layer < 3; layer++) {
        f32x4 acc[2][4];
#pragma unroll
        for (int m = 0; m < 2; m++)
#pragma unroll
            for (int nf = 0; nf < 4; nf++) acc[m][nf] = f32x4{0.f, 0.f, 0.f, 0.f};

        for (int kt = 0; kt < 4; kt++) {
            __syncthreads();
            {   // stage B k-tile [128n][32k] hi/lo
                int n = t >> 1, kh = (t & 1) * 16;
                size_t off = (size_t)layer * 16384 + n * 128 + kt * 32 + kh;
                const uint4* sh = reinterpret_cast<const uint4*>(Wh + off);
                const uint4* sl = reinterpret_cast<const uint4*>(Wl + off);
                uint4 h0 = sh[0], h1 = sh[1], l0 = sl[0], l1 = sl[1];
                *reinterpret_cast<uint4*>(&Bh[n][kh]) = h0;
                *reinterpret_cast<uint4*>(&Bh[n][kh + 8]) = h1;
                *reinterpret_cast<uint4*>(&Bl[n][kh]) = l0;
                *reinterpret_cast<uint4*>(&Bl[n][kh + 8]) = l1;
            }
            __syncthreads();
            short8 bh[4], bl[4];
#pragma unroll
            for (int nf = 0; nf < 4; nf++) {
                int n = wc * 64 + nf * 16 + l15;
                bh[nf] = *reinterpret_cast<const short8*>(&Bh[n][lg * 8]);
                bl[nf] = *reinterpret_cast<const short8*>(&Bl[n][lg * 8]);
            }
#pragma unroll
            for (int m = 0; m < 2; m++) {
                int row = wr * 32 + m * 16 + l15;
                float av[8];
                *reinterpret_cast<float4*>(&av[0]) =
                    *reinterpret_cast<const float4*>(&Xs[row][kt * 32 + lg * 8]);
                *reinterpret_cast<float4*>(&av[4]) =
                    *reinterpret_cast<const float4*>(&Xs[row][kt * 32 + lg * 8 + 4]);
                short8 ah, al; split8(av, ah, al);
#pragma unroll
                for (int nf = 0; nf < 4; nf++) {
                    acc[m][nf] = __builtin_amdgcn_mfma_f32_16x16x32_bf16(ah, bh[nf], acc[m][nf], 0, 0, 0);
                    acc[m][nf] = __builtin_amdgcn_mfma_f32_16x16x32_bf16(ah, bl[nf], acc[m][nf], 0, 0, 0);
                    acc[m][nf] = __builtin_amdgcn_mfma_f32_16x16x32_bf16(al, bh[nf], acc[m][nf], 0, 0, 0);
                }
            }
        }
        __syncthreads();
        float bv[4];
#pragma unroll
        for (int nf = 0; nf < 4; nf++) bv[nf] = bias[layer * 128 + wc * 64 + nf * 16 + l15];
        if (layer < 2) {
#pragma unroll
            for (int m = 0; m < 2; m++)
#pragma unroll
                for (int nf = 0; nf < 4; nf++)
#pragma unroll
                    for (int rr = 0; rr < 4; rr++) {
                        float v = fmaxf(acc[m][nf][rr] + bv[nf], 0.f);
                        Xs[wr * 32 + m * 16 + lg * 4 + rr][wc * 64 + nf * 16 + l15] = v;
                    }
        } else {
#pragma unroll
            for (int m = 0; m < 2; m++)
#pragma unroll
                for (int rr = 0; rr < 4; rr++) {
                    int gr = rb + wr * 32 + m * 16 + lg * 4 + rr;
                    if (gr < M) {
#pragma unroll
                        for (int nf = 0; nf < 4; nf++)
                            y[(size_t)gr * 128 + wc * 64 + nf * 16 + l15] = acc[m][nf][rr] + bv[nf];
                    }
                }
        }
    }
}

// ---------------- fused LSTM (gates GEMM bf16x3 + activations) ----------------
template <int NSTEP, bool FLIP>
__global__ __launch_bounds__(512, 2) void lstm_mfma(
    const float* __restrict__ A0, const float* __restrict__ A1, const float* __restrict__ A2,
    const unsigned short* __restrict__ Bh_g, const unsigned short* __restrict__ Bl_g,
    const float* __restrict__ bih, const float* __restrict__ bhh,
    float* __restrict__ c_st, float* __restrict__ h_out, int M)
{
    constexpr int KTOT = NSTEP * 32;
    __shared__ float Xs[128][36];
    __shared__ unsigned short Bhs[512][40];
    __shared__ unsigned short Bls[512][40];
    __shared__ float bsum[512];
    const int t = threadIdx.x;
    const int rb = blockIdx.x * 128;
    const int lane = t & 63, w = t >> 6, wr = w >> 1, wc = w & 1;
    const int l15 = lane & 15, lg = lane >> 4;
    bsum[t] = bih[t] + bhh[t];

    f32x4 acc[2][16];
#pragma unroll
    for (int m = 0; m < 2; m++)
#pragma unroll
        for (int nr = 0; nr < 16; nr++) acc[m][nr] = f32x4{0.f, 0.f, 0.f, 0.f};

    const int xrow = t >> 2, xc8 = (t & 3) * 8;
    int xgrow = rb + xrow; if (xgrow >= M) xgrow = M - 1;

    for (int kt = 0; kt < NSTEP; kt++) {
        __syncthreads();
        {   // stage X k-tile [128 rows][32 k] f32, segment-select
            int seg = kt >> 2;
            int kb = (kt & 3) * 32 + xc8;
            const float* src; size_t grow = (size_t)xgrow;
            if (NSTEP == 12) {
                if (seg == 0) src = A0;
                else if (seg == 1) {
                    src = A1;
                    if (FLIP) grow = (xgrow < NV) ? (size_t)(xgrow + NV) : (size_t)(xgrow - NV);
                } else src = A2;
            } else {
                src = seg ? A1 : A0;
            }
            const float4* sp = reinterpret_cast<const float4*>(src + grow * 128 + kb);
            float4 v0 = sp[0], v1 = sp[1];
            *reinterpret_cast<float4*>(&Xs[xrow][xc8]) = v0;
            *reinterpret_cast<float4*>(&Xs[xrow][xc8 + 4]) = v1;
        }
        {   // stage B k-tile [512n][32k] hi/lo
            size_t off = (size_t)t * KTOT + kt * 32;
            const uint4* sh = reinterpret_cast<const uint4*>(Bh_g + off);
            const uint4* sl = reinterpret_cast<const uint4*>(Bl_g + off);
            uint4 h0 = sh[0], h1 = sh[1], h2 = sh[2], h3 = sh[3];
            uint4 l0 = sl[0], l1 = sl[1], l2 = sl[2], l3 = sl[3];
            *reinterpret_cast<uint4*>(&Bhs[t][0])  = h0;
            *reinterpret_cast<uint4*>(&Bhs[t][8])  = h1;
            *reinterpret_cast<uint4*>(&Bhs[t][16]) = h2;
            *reinterpret_cast<uint4*>(&Bhs[t][24]) = h3;
            *reinterpret_cast<uint4*>(&Bls[t][0])  = l0;
            *reinterpret_cast<uint4*>(&Bls[t][8])  = l1;
            *reinterpret_cast<uint4*>(&Bls[t][16]) = l2;
            *reinterpret_cast<uint4*>(&Bls[t][24]) = l3;
        }
        __syncthreads();
        short8 ah[2], al[2];
#pragma unroll
        for (int m = 0; m < 2; m++) {
            int row = wr * 32 + m * 16 + l15;
            float av[8];
            *reinterpret_cast<float4*>(&av[0]) = *reinterpret_cast<const float4*>(&Xs[row][lg * 8]);
            *reinterpret_cast<float4*>(&av[4]) = *reinterpret_cast<const float4*>(&Xs[row][lg * 8 + 4]);
            split8(av, ah[m], al[m]);
        }
#pragma unroll
        for (int nr = 0; nr < 16; nr++) {
            int g = nr >> 2, nf = nr & 3;
            int n = g * 128 + wc * 64 + nf * 16 + l15;
            short8 bh = *reinterpret_cast<const short8*>(&Bhs[n][lg * 8]);
            short8 bl = *reinterpret_cast<const short8*>(&Bls[n][lg * 8]);
#pragma unroll
            for (int m = 0; m < 2; m++) {
                acc[m][nr] = __builtin_amdgcn_mfma_f32_16x16x32_bf16(ah[m], bh, acc[m][nr], 0, 0, 0);
                acc[m][nr] = __builtin_amdgcn_mfma_f32_16x16x32_bf16(ah[m], bl, acc[m][nr], 0, 0, 0);
                acc[m][nr] = __builtin_amdgcn_mfma_f32_16x16x32_bf16(al[m], bh, acc[m][nr], 0, 0, 0);
            }
        }
    }

    // activations + state update
#pragma unroll
    for (int m = 0; m < 2; m++)
#pragma unroll
        for (int rr = 0; rr < 4; rr++) {
            int gr = rb + wr * 32 + m * 16 + lg * 4 + rr;
            if (gr >= M) continue;
#pragma unroll
            for (int nf = 0; nf < 4; nf++) {
                int colc = wc * 64 + nf * 16 + l15;
                float gi = acc[m][nf][rr]      + bsum[colc];
                float gf = acc[m][4 + nf][rr]  + bsum[128 + colc];
                float gg = acc[m][8 + nf][rr]  + bsum[256 + colc];
                float go = acc[m][12 + nf][rr] + bsum[384 + colc];
                size_t p = (size_t)gr * 128 + colc;
                float cold = c_st[p];
                float cn = sigf(gf) * cold + sigf(gi) * tanhf(gg);
                float hn = sigf(go) * tanhf(cn);
                c_st[p] = cn;
                h_out[p] = hn;
            }
        }
}

extern "C" void kernel_launch(void* const* d_in, const int* in_sizes, int n_in,
                              void* d_out, int out_size, void* d_ws, size_t ws_size,
                              hipStream_t stream)
{
    const float* l_pos   = (const float*)d_in[0];
    const float* l_neg   = (const float*)d_in[1];
    const float* c_emb   = (const float*)d_in[2];
    const float* l_mlp_W = (const float*)d_in[3];
    const float* l_mlp_b = (const float*)d_in[4];
    const float* c_mlp_W = (const float*)d_in[5];
    const float* c_mlp_b = (const float*)d_in[6];
    const float* l_Wih   = (const float*)d_in[7];
    const float* l_Whh   = (const float*)d_in[8];
    const float* l_bih   = (const float*)d_in[9];
    const float* l_bhh   = (const float*)d_in[10];
    const float* c_Wih   = (const float*)d_in[11];
    const float* c_Whh   = (const float*)d_in[12];
    const float* c_bih   = (const float*)d_in[13];
    const float* c_bhh   = (const float*)d_in[14];
    const int* pos_src   = (const int*)d_in[15];
    const int* pos_dst   = (const int*)d_in[16];
    const int* neg_src   = (const int*)d_in[17];
    const int* neg_dst   = (const int*)d_in[18];

    float* out  = (float*)d_out;
    float* l_hA = out;
    float* c_h  = out + (size_t)NL * 128;

    float* wsp = (float*)d_ws;
    float* l_hB  = wsp; wsp += (size_t)NL * 128;
    float* l_c   = wsp; wsp += (size_t)NL * 128;
    float* c_c   = wsp; wsp += (size_t)NC * 128;
    float* l_msg = wsp; wsp += (size_t)NL * 128;
    float* c_msg = wsp; wsp += (size_t)NC * 128;
    float* l2c   = wsp; wsp += (size_t)NC * 128;
    float* c2l = l_msg;  // reused after l_msg consumed (l2c gather reads l_msg BEFORE c2l gather writes)

    unsigned short* us = (unsigned short*)wsp;
    unsigned short* mlpLh = us; us += 3 * 128 * 128;
    unsigned short* mlpLl = us; us += 3 * 128 * 128;
    unsigned short* mlpCh = us; us += 3 * 128 * 128;
    unsigned short* mlpCl = us; us += 3 * 128 * 128;
    unsigned short* lstmLh = us; us += 512 * 384;
    unsigned short* lstmLl = us; us += 512 * 384;
    unsigned short* lstmCh = us; us += 512 * 256;
    unsigned short* lstmCl = us; us += 512 * 256;

    int* ip = (int*)us;
    int* cnt_c    = ip; ip += NC;
    int* rowptr_c = ip; ip += NC + 1;
    int* cur_c    = ip; ip += NC;
    int* eidx_c   = ip; ip += 2 * NE;
    int* cnt_l    = ip; ip += NL;
    int* rowptr_l = ip; ip += NL + 1;
    int* cur_l    = ip; ip += NL;
    int* eidx_l   = ip; ip += 2 * NE;
    int* part_c   = ip; ip += 256;
    int* part_l   = ip; ip += 256;

    // init states
    hipMemcpyAsync(l_hA, l_pos, (size_t)NV * 128 * 4, hipMemcpyDeviceToDevice, stream);
    hipMemcpyAsync(l_hA + (size_t)NV * 128, l_neg, (size_t)NV * 128 * 4, hipMemcpyDeviceToDevice, stream);
    hipMemcpyAsync(c_h, c_emb, (size_t)NC * 128 * 4, hipMemcpyDeviceToDevice, stream);
    hipMemsetAsync(l_c, 0, (size_t)NL * 128 * 4, stream);
    hipMemsetAsync(c_c, 0, (size_t)NC * 128 * 4, stream);

    // pack weights (once per call)
    pack_mlp_k<<<192, 256, 0, stream>>>(l_mlp_W, mlpLh, mlpLl);
    pack_mlp_k<<<192, 256, 0, stream>>>(c_mlp_W, mlpCh, mlpCl);
    pack_lstm_k<<<768, 256, 0, stream>>>(l_Wih, l_Whh, 256, 384, lstmLh, lstmLl);
    pack_lstm_k<<<512, 256, 0, stream>>>(c_Wih, c_Whh, 128, 256, lstmCh, lstmCl);

    // ---- CSR build (once per call; graph static across rounds) ----
    hipMemsetAsync(cnt_c, 0, NC * sizeof(int), stream);
    hipMemsetAsync(cnt_l, 0, NL * sizeof(int), stream);
    constexpr int EB = (NE + 255) / 256;
    csr_hist_k<<<EB, 256, 0, stream>>>(pos_src, pos_dst, neg_src, neg_dst, cnt_c, cnt_l);
    constexpr int NBC = (NC + 1023) / 1024;  // 196
    constexpr int NBL = (NL + 1023) / 1024;  // 98
    scan_p1<<<NBC, 256, 0, stream>>>(cnt_c, part_c, NC);
    scan_p2<<<1, 256, 0, stream>>>(part_c, NBC, rowptr_c + NC);
    scan_p3<<<NBC, 256, 0, stream>>>(cnt_c, part_c, rowptr_c, cur_c, NC);
    scan_p1<<<NBL, 256, 0, stream>>>(cnt_l, part_l, NL);
    scan_p2<<<1, 256, 0, stream>>>(part_l, NBL, rowptr_l + NL);
    scan_p3<<<NBL, 256, 0, stream>>>(cnt_l, part_l, rowptr_l, cur_l, NL);
    csr_fill_k<<<EB, 256, 0, stream>>>(pos_src, pos_dst, neg_src, neg_dst,
                                       cur_c, eidx_c, cur_l, eidx_l);

    float* l_cur = l_hA;
    float* l_nxt = l_hB;

    for (int r = 0; r < NROUNDS; r++) {
        mlp3<<<(NL + 63) / 64, 256, 0, stream>>>(l_cur, mlpLh, mlpLl, l_mlp_b, l_msg, NL);
        mlp3<<<(NC + 63) / 64, 256, 0, stream>>>(c_h, mlpCh, mlpCl, c_mlp_b, c_msg, NC);

        // l2c[c] = sum over eidx_c segment of l_msg rows (reads l_msg, writes l2c)
        gather_sum_k<<<NC * 64 / 256, 256, 0, stream>>>(l_msg, rowptr_c, eidx_c, l2c, NC);
        // c2l[v] = sum over eidx_l segment of c_msg rows (writes into l_msg space AFTER it's dead)
        gather_sum_k<<<NL * 64 / 256, 256, 0, stream>>>(c_msg, rowptr_l, eidx_l, c2l, NL);

        lstm_mfma<12, true><<<(NL + 127) / 128, 512, 0, stream>>>(
            c2l, l_cur, l_cur, lstmLh, lstmLl, l_bih, l_bhh, l_c, l_nxt, NL);
        lstm_mfma<8, false><<<(NC + 127) / 128, 512, 0, stream>>>(
            l2c, c_h, nullptr, lstmCh, lstmCl, c_bih, c_bhh, c_c, c_h, NC);

        float* t2 = l_cur; l_cur = l_nxt; l_nxt = t2;
    }
    (void)in_sizes; (void)n_in; (void)out_size; (void)ws_size;
}